// Round 5
// baseline (425.622 us; speedup 1.0000x reference)
//
#include <hip/hip_runtime.h>
#include <hip/hip_bf16.h>

#define EMB 768
#define NHEADS 8
#define HDIM 96
#define SEQ 2048
#define BATCH 4
#define QKV_COLS 2304
#define PB ((size_t)SEQ * EMB)   // per-batch elements

typedef _Float16 f16;
typedef _Float16 f16x8 __attribute__((ext_vector_type(8)));
typedef float f32x4 __attribute__((ext_vector_type(4)));

__device__ __forceinline__ void gl_lds16(const f16* g, f16* l) {
  __builtin_amdgcn_global_load_lds((const __attribute__((address_space(1))) void*)g,
                                   (__attribute__((address_space(3))) void*)l, 16, 0, 0);
}
__device__ __forceinline__ f32x4 shflx4(f32x4 v, int m) {
  f32x4 r;
  r[0] = __shfl_xor(v[0], m); r[1] = __shfl_xor(v[1], m);
  r[2] = __shfl_xor(v[2], m); r[3] = __shfl_xor(v[3], m);
  return r;
}
__device__ __forceinline__ f32x4 vmax4(f32x4 a, f32x4 b) {
  f32x4 r;
  r[0] = fmaxf(a[0], b[0]); r[1] = fmaxf(a[1], b[1]);
  r[2] = fmaxf(a[2], b[2]); r[3] = fmaxf(a[3], b[3]);
  return r;
}

// ---------------- conversions ----------------
__global__ __launch_bounds__(256) void conv_x8_k(const float* __restrict__ in, size_t in_off,
                                                 f16* __restrict__ out, int n8) {
  int i = blockIdx.x * 256 + threadIdx.x;
  if (i >= n8) return;
  const float4 a = *(const float4*)(in + in_off + (size_t)i * 8);
  const float4 b = *(const float4*)(in + in_off + (size_t)i * 8 + 4);
  f16x8 o;
  o[0] = (f16)a.x; o[1] = (f16)a.y; o[2] = (f16)a.z; o[3] = (f16)a.w;
  o[4] = (f16)b.x; o[5] = (f16)b.y; o[6] = (f16)b.z; o[7] = (f16)b.w;
  *(f16x8*)(out + (size_t)i * 8) = o;
}

// qkv weight: transpose + column-permute. out[col'][r], col' = s*768+h*96+d,
// original col c = h*288+d*3+s. Output-indexed -> coalesced 16B writes.
__global__ __launch_bounds__(256) void wqkv_perm_k(const float* __restrict__ in,
                                                   f16* __restrict__ out) {
  int t = blockIdx.x * 256 + threadIdx.x;          // 0 .. 2304*96-1
  if (t >= QKV_COLS * (EMB / 8)) return;
  const int colp = t / (EMB / 8);
  const int r8 = (t - colp * (EMB / 8)) * 8;
  const int s = colp / 768, rem = colp - s * 768;
  const int h = rem / 96, d = rem - h * 96;
  const int c = h * 288 + d * 3 + s;
  f16x8 o;
#pragma unroll
  for (int i = 0; i < 8; i++) o[i] = (f16)in[(size_t)(r8 + i) * QKV_COLS + c];
  *(f16x8*)(out + (size_t)colp * EMB + r8) = o;
}

// proj weight: plain transpose, output-indexed.
__global__ __launch_bounds__(256) void wproj_t_k(const float* __restrict__ in,
                                                 f16* __restrict__ out) {
  int t = blockIdx.x * 256 + threadIdx.x;          // 0 .. 768*96-1
  if (t >= EMB * (EMB / 8)) return;
  const int cp = t / (EMB / 8);
  const int r8 = (t - cp * (EMB / 8)) * 8;
  f16x8 o;
#pragma unroll
  for (int i = 0; i < 8; i++) o[i] = (f16)in[(size_t)(r8 + i) * EMB + cp];
  *(f16x8*)(out + (size_t)cp * EMB + r8) = o;
}

// bias: permute qkv bias to col' space; copy proj bias.
__global__ __launch_bounds__(256) void bias_perm_k(const float* __restrict__ bq_in,
                                                   float* __restrict__ bq_out,
                                                   const float* __restrict__ bp_in,
                                                   float* __restrict__ bp_out) {
  int i = blockIdx.x * 256 + threadIdx.x;
  if (i < QKV_COLS) {
    const int s = i / 768, rem = i - s * 768;
    const int h = rem / 96, d = rem - h * 96;
    bq_out[i] = bq_in[h * 288 + d * 3 + s];
  }
  if (i < EMB) bp_out[i] = bp_in[i];
}

// ---------------- bt-GEMM: C[M,N] = A[M,K] @ Bt[N,K]^T + bias ----------------
// MODE 0: fp32 store to Cout [M,N], A row-major [M][Kd]
// MODE 1 (permuted qkv): tile_n < 1536 -> QK[row][1536] direct (coalesced);
//                        tile_n >= 1536 -> V: LDS transpose -> Vt[bh][d][n] coalesced
// MODE 2: like MODE 0 but A is head-major [b*8+h][2048][96]; k -> (h = k/96, d = k%96).
//         32-wide k-chunks never straddle heads (96 = 3*32), so h = k0/96 per chunk.
template<int MODE>
__global__ __launch_bounds__(256) void gemm_bt(
    const f16* __restrict__ A, const f16* __restrict__ Bt,
    const float* __restrict__ bias, float* __restrict__ Cout,
    f16* __restrict__ QK, f16* __restrict__ Vt,
    int M, int N, int Kd)
{
  __shared__ f16 smem[MODE == 1 ? 17408 : 8192];   // sA[4096]+sB[4096]; V-epilogue reuses as sT[128][136]
  f16* sA = smem;
  f16* sB = smem + 4096;
  const int tid  = threadIdx.x;
  const int wave = tid >> 6, lane = tid & 63;
  const int quad = lane >> 4, l16 = lane & 15;
  const int tile_m = blockIdx.y * 128, tile_n = blockIdx.x * 128;
  const int wm = (wave >> 1) * 64, wn = (wave & 1) * 64;

  f32x4 acc[4][4];
  for (int i = 0; i < 4; i++)
    for (int j = 0; j < 4; j++)
      acc[i][j] = f32x4{0.f, 0.f, 0.f, 0.f};

  for (int k0 = 0; k0 < Kd; k0 += 32) {
    __syncthreads();
#pragma unroll
    for (int it = 0; it < 2; it++) {
      const int ch  = (it * 4 + wave) * 64 + lane;   // 0..511
      const int row = ch >> 2, c8 = (ch & 3) * 8;
      if (MODE == 2) {
        const int grow = tile_m + row;
        const int bb = grow >> 11, n = grow & 2047;
        const int hh = k0 / 96, d0 = k0 - hh * 96 + c8;
        gl_lds16(A + ((size_t)(bb * NHEADS + hh) * SEQ + n) * HDIM + d0,
                 &sA[(it * 4 + wave) * 512]);
      } else {
        gl_lds16(A + (size_t)(tile_m + row) * Kd + k0 + c8, &sA[(it * 4 + wave) * 512]);
      }
      gl_lds16(Bt + (size_t)(tile_n + row) * Kd + k0 + c8, &sB[(it * 4 + wave) * 512]);
    }
    __syncthreads();

    f16x8 af[4], bfr[4];
    for (int i = 0; i < 4; i++) af[i]  = *(const f16x8*)&sA[(wm + i * 16 + l16) * 32 + quad * 8];
    for (int j = 0; j < 4; j++) bfr[j] = *(const f16x8*)&sB[(wn + j * 16 + l16) * 32 + quad * 8];
    for (int i = 0; i < 4; i++)
      for (int j = 0; j < 4; j++)
        acc[i][j] = __builtin_amdgcn_mfma_f32_16x16x32_f16(af[i], bfr[j], acc[i][j], 0, 0, 0);
  }

  // epilogue: C layout col=lane&15, row=quad*4+reg
  if (MODE == 1 && tile_n >= 1536) {
    // ---- V tile: LDS transpose then coalesced Vt writes ----
    __syncthreads();   // sA/sB dead, safe to overwrite
    f16* sT = smem;    // [128][136]
    for (int j = 0; j < 4; j++) {
      const int cl = wn + j * 16 + l16;
      const float bv = bias[tile_n + cl];
      for (int i = 0; i < 4; i++)
        for (int r = 0; r < 4; r++)
          sT[cl * 136 + wm + i * 16 + quad * 4 + r] = (f16)(acc[i][j][r] + bv);
    }
    __syncthreads();
    const int bb = tile_m >> 11;          // group-local batch
    const int n0 = tile_m & 2047;
#pragma unroll
    for (int l = 0; l < 8; l++) {
      const int cc = l * 256 + tid;       // 0..2047 chunks of 8 f16
      const int rh = cc >> 4, nof = (cc & 15) * 8;
      const int hd = (tile_n - 1536) + rh;
      const int h = hd / 96, d = hd - h * 96;
      f16x8 v = *(const f16x8*)&sT[rh * 136 + nof];
      *(f16x8*)(Vt + ((size_t)(bb * NHEADS + h) * HDIM + d) * SEQ + n0 + nof) = v;
    }
  } else {
    for (int j = 0; j < 4; j++) {
      const int col = tile_n + wn + j * 16 + l16;
      const float bv = bias[col];
      for (int i = 0; i < 4; i++) {
        for (int r = 0; r < 4; r++) {
          const int row = tile_m + wm + i * 16 + quad * 4 + r;
          const float fv = acc[i][j][r] + bv;
          if (MODE != 1) Cout[(size_t)row * N + col] = fv;
          else           QK  [(size_t)row * 1536 + col] = (f16)fv;  // Q cols 0..767, K 768..1535
        }
      }
    }
  }
}

// ---------------- flash attention ----------------
// Round-4-proven math; this round adds ONLY latency-hiding reorderings
// (no per-lane value changes):
//  (1) async K-stage (T14): next tile prefetched into 3 uint4 regs during the
//      compute phase; stage phase is just ds_write + issue-next-loads.
//  (2) batched register preloads: kf in groups of 4, vf in groups of 6, both
//      pf upfront -> 4-6 memory ops in flight (was 1-2 at VGPR=64). Arrays are
//      statically indexed; peak VGPR ~116 < 128 cap of launch_bounds(512,4).
// Geometry/output layout unchanged from round 4 (512 thr, 8 waves x 16 q-rows,
// XCD swizzle, head-major Out).
__global__ __launch_bounds__(512, 4) void attn_k(
    const f16* __restrict__ QK, const f16* __restrict__ Vt,
    f16* __restrict__ Out /* [nb*8][2048][96] f16 */, int nbh)
{
  __shared__ f16 sK[128][104];   // 26624 B
  __shared__ f16 sP[128][72];    // 18432 B
  const int tid  = threadIdx.x;
  const int wave = tid >> 6, lane = tid & 63;
  const int quad = lane >> 4, l16 = lane & 15;

  const int bid = blockIdx.x;
  const int xcd = bid & 7, idx = bid >> 3;   // dispatch round-robins XCDs on bid%8
  const int bh  = xcd * (nbh >> 3) + (idx >> 4);
  const int qt  = idx & 15;
  const int b = bh >> 3, h = bh & 7;

  const int wrow = wave * 16;                // this wave's q-row base within the 128-tile

  const f16* Qb = QK + (size_t)(b * SEQ + qt * 128 + wrow) * 1536 + h * 96;
  const f16* Kb = QK + (size_t)(b * SEQ) * 1536 + 768 + h * 96;
  const f16* Vb = Vt + (size_t)bh * HDIM * SEQ;

  f16x8 qf[3];
#pragma unroll
  for (int kc = 0; kc < 3; kc++)
    qf[kc] = *(const f16x8*)(Qb + (size_t)l16 * 1536 + kc * 32 + quad * 8);

  f32x4 oacc[6];
#pragma unroll
  for (int dj = 0; dj < 6; dj++) oacc[dj] = f32x4{0.f, 0.f, 0.f, 0.f};
  f32x4 m_run = f32x4{-1e30f, -1e30f, -1e30f, -1e30f};
  f32x4 l_run = f32x4{0.f, 0.f, 0.f, 0.f};

  // stage-chunk mapping (fixed per thread): c = i*512+tid -> row=c/12, col=(c%12)*8
  int srow[3], scol[3];
#pragma unroll
  for (int i = 0; i < 3; i++) {
    const int c = i * 512 + tid;
    srow[i] = c / 12; scol[i] = (c - srow[i] * 12) * 8;
  }

  // prologue: prefetch K tile 0 into regs
  uint4 kreg[3];
#pragma unroll
  for (int i = 0; i < 3; i++)
    kreg[i] = *(const uint4*)(Kb + (size_t)srow[i] * 1536 + scol[i]);

  for (int kt = 0; kt < SEQ / 128; kt++) {
    __syncthreads();                         // all waves done reading sK (prev iter)
#pragma unroll
    for (int i = 0; i < 3; i++)
      *(uint4*)&sK[srow[i]][scol[i]] = kreg[i];
    if (kt < SEQ / 128 - 1) {                // issue next-tile loads; wait lands next iter
      const f16* nbase = Kb + (size_t)((kt + 1) * 128) * 1536;
#pragma unroll
      for (int i = 0; i < 3; i++)
        kreg[i] = *(const uint4*)(nbase + (size_t)srow[i] * 1536 + scol[i]);
    }
    __syncthreads();                         // sK ready

    // ---- QK^T with batched kf reads (4 in flight) ----
    f32x4 sacc[8];
#pragma unroll
    for (int j = 0; j < 8; j++) sacc[j] = f32x4{0.f, 0.f, 0.f, 0.f};
#pragma unroll
    for (int kc = 0; kc < 3; kc++) {
#pragma unroll
      for (int jb = 0; jb < 2; jb++) {
        f16x8 kf[4];
#pragma unroll
        for (int u = 0; u < 4; u++)
          kf[u] = *(const f16x8*)&sK[(jb * 4 + u) * 16 + l16][kc * 32 + quad * 8];
#pragma unroll
        for (int u = 0; u < 4; u++)
          sacc[jb * 4 + u] = __builtin_amdgcn_mfma_f32_16x16x32_f16(qf[kc], kf[u], sacc[jb * 4 + u], 0, 0, 0);
      }
    }

    // ---- stats: max, alpha, rescale (identical values to round 4) ----
    f32x4 vmx = sacc[0];
#pragma unroll
    for (int j = 1; j < 8; j++) vmx = vmax4(vmx, sacc[j]);
    for (int m = 1; m < 16; m <<= 1) vmx = vmax4(vmx, shflx4(vmx, m));
    const f32x4 nm = vmax4(m_run, vmx);
    f32x4 alpha;
    alpha[0] = __expf(m_run[0] - nm[0]); alpha[1] = __expf(m_run[1] - nm[1]);
    alpha[2] = __expf(m_run[2] - nm[2]); alpha[3] = __expf(m_run[3] - nm[3]);
    m_run = nm;
    l_run *= alpha;
    f32x4 rsv = f32x4{0.f, 0.f, 0.f, 0.f};
#pragma unroll
    for (int dj = 0; dj < 6; dj++) oacc[dj] *= alpha;

    // ---- two 64-k chunks: write P half -> PV half (sP time-multiplexed) ----
#pragma unroll
    for (int c2 = 0; c2 < 2; c2++) {
      const int prow = wrow + quad * 4;
#pragma unroll
      for (int jl = 0; jl < 4; jl++) {
        const int j = c2 * 4 + jl;
        f32x4 p;
        p[0] = __expf(sacc[j][0] - m_run[0]);
        p[1] = __expf(sacc[j][1] - m_run[1]);
        p[2] = __expf(sacc[j][2] - m_run[2]);
        p[3] = __expf(sacc[j][3] - m_run[3]);
        rsv += p;
        sP[prow + 0][jl * 16 + l16] = (f16)p[0];
        sP[prow + 1][jl * 16 + l16] = (f16)p[1];
        sP[prow + 2][jl * 16 + l16] = (f16)p[2];
        sP[prow + 3][jl * 16 + l16] = (f16)p[3];
      }
      // both pf reads issued together (compiler orders them after the writes)
      f16x8 pf[2];
      pf[0] = *(const f16x8*)&sP[wrow + l16][0 * 32 + quad * 8];
      pf[1] = *(const f16x8*)&sP[wrow + l16][1 * 32 + quad * 8];
#pragma unroll
      for (int kc2 = 0; kc2 < 2; kc2++) {
        f16x8 vf[6];
#pragma unroll
        for (int dj = 0; dj < 6; dj++)
          vf[dj] = *(const f16x8*)(Vb + (size_t)(dj * 16 + l16) * SEQ
                                   + kt * 128 + c2 * 64 + kc2 * 32 + quad * 8);
#pragma unroll
        for (int dj = 0; dj < 6; dj++)
          oacc[dj] = __builtin_amdgcn_mfma_f32_16x16x32_f16(pf[kc2], vf[dj], oacc[dj], 0, 0, 0);
      }
    }

    // ---- finish row sums ----
    for (int m = 1; m < 16; m <<= 1) rsv += shflx4(rsv, m);
    l_run += rsv;
  }

  const float inv_scale = 0.10206207261596577f;  // 1/sqrt(96), applied AFTER softmax per ref
#pragma unroll
  for (int r = 0; r < 4; r++) {
    const int qrow = qt * 128 + wrow + quad * 4 + r;
    const float invl = inv_scale / l_run[r];
    const size_t base = ((size_t)bh * SEQ + qrow) * HDIM;   // head-major out
#pragma unroll
    for (int dj = 0; dj < 6; dj++)
      Out[base + dj * 16 + l16] = (f16)(oacc[dj][r] * invl);
  }
}

// ---------------- launch ----------------
extern "C" void kernel_launch(void* const* d_in, const int* in_sizes, int n_in,
                              void* d_out, int out_size, void* d_ws, size_t ws_size,
                              hipStream_t stream) {
  const float* x      = (const float*)d_in[0];
  const float* w_qkv  = (const float*)d_in[1];
  const float* b_qkv  = (const float*)d_in[2];
  const float* w_proj = (const float*)d_in[3];
  const float* b_proj = (const float*)d_in[4];
  float* outF = (float*)d_out;   // fp32 output

  const size_t fixed = 256 + (size_t)QKV_COLS * EMB * 2 + (size_t)EMB * EMB * 2
                     + QKV_COLS * 4 + EMB * 4 + 256;
  const size_t perb = (size_t)4 * PB * 2;  // QK(2) + Vt(1) + attn(1) per batch, in PB units
  int nb = (ws_size >= fixed + 4 * perb) ? 4 : (ws_size >= fixed + 2 * perb) ? 2 : 1;

  char* ws = (char*)d_ws;
  ws += 256;
  f16*   wqkvT  = (f16*)ws;   ws += (size_t)QKV_COLS * EMB * 2;
  f16*   wprojT = (f16*)ws;   ws += (size_t)EMB * EMB * 2;
  float* bq     = (float*)ws; ws += (size_t)QKV_COLS * 4;
  float* bp     = (float*)ws; ws += (size_t)EMB * 4 + 256;
  f16* QK   = (f16*)ws;       ws += (size_t)nb * 2 * PB * 2;   // [nb*2048][1536]
  f16* Vt   = (f16*)ws;       ws += (size_t)nb * PB * 2;       // [nb*8][96][2048]
  f16* attn = (f16*)ws;       ws += (size_t)nb * PB * 2;       // [nb*8][2048][96] head-major

  wqkv_perm_k<<<(QKV_COLS * (EMB / 8) + 255) / 256, 256, 0, stream>>>(w_qkv, wqkvT);
  wproj_t_k<<<(EMB * (EMB / 8) + 255) / 256, 256, 0, stream>>>(w_proj, wprojT);
  bias_perm_k<<<(QKV_COLS + 255) / 256, 256, 0, stream>>>(b_qkv, bq, b_proj, bp);

  for (int outer = 0; outer < BATCH / nb; outer++) {
    const int bbase = outer * nb;
    const size_t goff = (size_t)bbase * PB;
    f16* xg = (f16*)(outF + goff);           // stage f16 x inside fp32 out region (dead before proj)
    const int n8 = (int)((size_t)nb * PB / 8);
    conv_x8_k<<<(n8 + 255) / 256, 256, 0, stream>>>(x, goff, xg, n8);

    dim3 g1(QKV_COLS / 128, nb * SEQ / 128);
    gemm_bt<1><<<g1, 256, 0, stream>>>(xg, wqkvT, bq, nullptr, QK, Vt,
                                       nb * SEQ, QKV_COLS, EMB);

    attn_k<<<dim3(16 * nb * NHEADS), 512, 0, stream>>>(QK, Vt, attn, nb * NHEADS);

    dim3 g3(EMB / 128, nb * SEQ / 128);
    gemm_bt<2><<<g3, 256, 0, stream>>>(attn, wprojT, bp, outF + goff,
                                       nullptr, nullptr,
                                       nb * SEQ, EMB, EMB);
  }
}

// Round 7
// 418.382 us; speedup vs baseline: 1.0173x; 1.0173x over previous
//
#include <hip/hip_runtime.h>
#include <hip/hip_bf16.h>

#define EMB 768
#define NHEADS 8
#define HDIM 96
#define SEQ 2048
#define BATCH 4
#define QKV_COLS 2304
#define PB ((size_t)SEQ * EMB)   // per-batch elements

typedef _Float16 f16;
typedef _Float16 f16x8 __attribute__((ext_vector_type(8)));
typedef float f32x4 __attribute__((ext_vector_type(4)));

__device__ __forceinline__ void gl_lds16(const f16* g, f16* l) {
  __builtin_amdgcn_global_load_lds((const __attribute__((address_space(1))) void*)g,
                                   (__attribute__((address_space(3))) void*)l, 16, 0, 0);
}
__device__ __forceinline__ f32x4 shflx4(f32x4 v, int m) {
  f32x4 r;
  r[0] = __shfl_xor(v[0], m); r[1] = __shfl_xor(v[1], m);
  r[2] = __shfl_xor(v[2], m); r[3] = __shfl_xor(v[3], m);
  return r;
}
__device__ __forceinline__ f32x4 vmax4(f32x4 a, f32x4 b) {
  f32x4 r;
  r[0] = fmaxf(a[0], b[0]); r[1] = fmaxf(a[1], b[1]);
  r[2] = fmaxf(a[2], b[2]); r[3] = fmaxf(a[3], b[3]);
  return r;
}

// ---------------- conversions ----------------
__global__ __launch_bounds__(256) void conv_x8_k(const float* __restrict__ in, size_t in_off,
                                                 f16* __restrict__ out, int n8) {
  int i = blockIdx.x * 256 + threadIdx.x;
  if (i >= n8) return;
  const float4 a = *(const float4*)(in + in_off + (size_t)i * 8);
  const float4 b = *(const float4*)(in + in_off + (size_t)i * 8 + 4);
  f16x8 o;
  o[0] = (f16)a.x; o[1] = (f16)a.y; o[2] = (f16)a.z; o[3] = (f16)a.w;
  o[4] = (f16)b.x; o[5] = (f16)b.y; o[6] = (f16)b.z; o[7] = (f16)b.w;
  *(f16x8*)(out + (size_t)i * 8) = o;
}

// qkv weight: transpose + column-permute. out[col'][r], col' = s*768+h*96+d,
// original col c = h*288+d*3+s. Output-indexed -> coalesced 16B writes.
__global__ __launch_bounds__(256) void wqkv_perm_k(const float* __restrict__ in,
                                                   f16* __restrict__ out) {
  int t = blockIdx.x * 256 + threadIdx.x;          // 0 .. 2304*96-1
  if (t >= QKV_COLS * (EMB / 8)) return;
  const int colp = t / (EMB / 8);
  const int r8 = (t - colp * (EMB / 8)) * 8;
  const int s = colp / 768, rem = colp - s * 768;
  const int h = rem / 96, d = rem - h * 96;
  const int c = h * 288 + d * 3 + s;
  f16x8 o;
#pragma unroll
  for (int i = 0; i < 8; i++) o[i] = (f16)in[(size_t)(r8 + i) * QKV_COLS + c];
  *(f16x8*)(out + (size_t)colp * EMB + r8) = o;
}

// proj weight: plain transpose, output-indexed.
__global__ __launch_bounds__(256) void wproj_t_k(const float* __restrict__ in,
                                                 f16* __restrict__ out) {
  int t = blockIdx.x * 256 + threadIdx.x;          // 0 .. 768*96-1
  if (t >= EMB * (EMB / 8)) return;
  const int cp = t / (EMB / 8);
  const int r8 = (t - cp * (EMB / 8)) * 8;
  f16x8 o;
#pragma unroll
  for (int i = 0; i < 8; i++) o[i] = (f16)in[(size_t)(r8 + i) * EMB + cp];
  *(f16x8*)(out + (size_t)cp * EMB + r8) = o;
}

// bias: permute qkv bias to col' space; copy proj bias.
__global__ __launch_bounds__(256) void bias_perm_k(const float* __restrict__ bq_in,
                                                   float* __restrict__ bq_out,
                                                   const float* __restrict__ bp_in,
                                                   float* __restrict__ bp_out) {
  int i = blockIdx.x * 256 + threadIdx.x;
  if (i < QKV_COLS) {
    const int s = i / 768, rem = i - s * 768;
    const int h = rem / 96, d = rem - h * 96;
    bq_out[i] = bq_in[h * 288 + d * 3 + s];
  }
  if (i < EMB) bp_out[i] = bp_in[i];
}

// ---------------- bt-GEMM: C[M,N] = A[M,K] @ Bt[N,K]^T + bias ----------------
// MODE 0: fp32 store to Cout [M,N], A row-major [M][Kd]
// MODE 1 (permuted qkv): tile_n < 1536 -> QK[row][1536] direct (coalesced);
//                        tile_n >= 1536 -> V: LDS transpose -> Vt[bh][d][n] coalesced
// MODE 2: like MODE 0 but A is head-major [b*8+h][2048][96]; k -> (h = k/96, d = k%96).
//         32-wide k-chunks never straddle heads (96 = 3*32), so h = k0/96 per chunk.
template<int MODE>
__global__ __launch_bounds__(256) void gemm_bt(
    const f16* __restrict__ A, const f16* __restrict__ Bt,
    const float* __restrict__ bias, float* __restrict__ Cout,
    f16* __restrict__ QK, f16* __restrict__ Vt,
    int M, int N, int Kd)
{
  __shared__ f16 smem[MODE == 1 ? 17408 : 8192];   // sA[4096]+sB[4096]; V-epilogue reuses as sT[128][136]
  f16* sA = smem;
  f16* sB = smem + 4096;
  const int tid  = threadIdx.x;
  const int wave = tid >> 6, lane = tid & 63;
  const int quad = lane >> 4, l16 = lane & 15;
  const int tile_m = blockIdx.y * 128, tile_n = blockIdx.x * 128;
  const int wm = (wave >> 1) * 64, wn = (wave & 1) * 64;

  f32x4 acc[4][4];
  for (int i = 0; i < 4; i++)
    for (int j = 0; j < 4; j++)
      acc[i][j] = f32x4{0.f, 0.f, 0.f, 0.f};

  for (int k0 = 0; k0 < Kd; k0 += 32) {
    __syncthreads();
#pragma unroll
    for (int it = 0; it < 2; it++) {
      const int ch  = (it * 4 + wave) * 64 + lane;   // 0..511
      const int row = ch >> 2, c8 = (ch & 3) * 8;
      if (MODE == 2) {
        const int grow = tile_m + row;
        const int bb = grow >> 11, n = grow & 2047;
        const int hh = k0 / 96, d0 = k0 - hh * 96 + c8;
        gl_lds16(A + ((size_t)(bb * NHEADS + hh) * SEQ + n) * HDIM + d0,
                 &sA[(it * 4 + wave) * 512]);
      } else {
        gl_lds16(A + (size_t)(tile_m + row) * Kd + k0 + c8, &sA[(it * 4 + wave) * 512]);
      }
      gl_lds16(Bt + (size_t)(tile_n + row) * Kd + k0 + c8, &sB[(it * 4 + wave) * 512]);
    }
    __syncthreads();

    f16x8 af[4], bfr[4];
    for (int i = 0; i < 4; i++) af[i]  = *(const f16x8*)&sA[(wm + i * 16 + l16) * 32 + quad * 8];
    for (int j = 0; j < 4; j++) bfr[j] = *(const f16x8*)&sB[(wn + j * 16 + l16) * 32 + quad * 8];
    for (int i = 0; i < 4; i++)
      for (int j = 0; j < 4; j++)
        acc[i][j] = __builtin_amdgcn_mfma_f32_16x16x32_f16(af[i], bfr[j], acc[i][j], 0, 0, 0);
  }

  // epilogue: C layout col=lane&15, row=quad*4+reg
  if (MODE == 1 && tile_n >= 1536) {
    // ---- V tile: LDS transpose then coalesced Vt writes ----
    __syncthreads();   // sA/sB dead, safe to overwrite
    f16* sT = smem;    // [128][136]
    for (int j = 0; j < 4; j++) {
      const int cl = wn + j * 16 + l16;
      const float bv = bias[tile_n + cl];
      for (int i = 0; i < 4; i++)
        for (int r = 0; r < 4; r++)
          sT[cl * 136 + wm + i * 16 + quad * 4 + r] = (f16)(acc[i][j][r] + bv);
    }
    __syncthreads();
    const int bb = tile_m >> 11;          // group-local batch
    const int n0 = tile_m & 2047;
#pragma unroll
    for (int l = 0; l < 8; l++) {
      const int cc = l * 256 + tid;       // 0..2047 chunks of 8 f16
      const int rh = cc >> 4, nof = (cc & 15) * 8;
      const int hd = (tile_n - 1536) + rh;
      const int h = hd / 96, d = hd - h * 96;
      f16x8 v = *(const f16x8*)&sT[rh * 136 + nof];
      *(f16x8*)(Vt + ((size_t)(bb * NHEADS + h) * HDIM + d) * SEQ + n0 + nof) = v;
    }
  } else {
    for (int j = 0; j < 4; j++) {
      const int col = tile_n + wn + j * 16 + l16;
      const float bv = bias[col];
      for (int i = 0; i < 4; i++) {
        for (int r = 0; r < 4; r++) {
          const int row = tile_m + wm + i * 16 + quad * 4 + r;
          const float fv = acc[i][j][r] + bv;
          if (MODE != 1) Cout[(size_t)row * N + col] = fv;
          else           QK  [(size_t)row * 1536 + col] = (f16)fv;  // Q cols 0..767, K 768..1535
        }
      }
    }
  }
}

// ---------------- flash attention ----------------
// Combines the two cross-round-proven wins (never yet together):
//  - round-4 geometry: 512 thr = 8 waves x 16 q-rows, head-major Out, XCD swizzle
//    -> 2 blocks/CU x 8 waves = 16 waves/CU.
//  - round-0 per-kt flow: FULL-width sP, ONE P-write->PV phase per kt (the r3/r4
//    two-phase sP split cost ~+30 us of extra lgkm-drain exposure).
// New: sP padded to 140 f16/row (70 dwords = 6 mod 32): the 4 quad-rows of the
// scalar P-write land on disjoint 8-bank ranges {0-7,24-31,16-23,8-15} -> the
// 4-way write conflict (7.9M cycles in r4) drops to the free 2-lane/dword case;
// pf reads also spread to 16 distinct even bank-starts.
// Round-5's forced reg-batching/prefetch REVERTED (VGPR stuck at 64 + ~100 MB
// scratch writeback traffic).
__global__ __launch_bounds__(512, 4) void attn_k(
    const f16* __restrict__ QK, const f16* __restrict__ Vt,
    f16* __restrict__ Out /* [nb*8][2048][96] f16 */, int nbh)
{
  __shared__ f16 sK[128][104];   // 26624 B
  __shared__ f16 sP[128][140];   // 35840 B; total 62464 B -> 2 blocks/CU
  const int tid  = threadIdx.x;
  const int wave = tid >> 6, lane = tid & 63;
  const int quad = lane >> 4, l16 = lane & 15;

  const int bid = blockIdx.x;
  const int xcd = bid & 7, idx = bid >> 3;   // dispatch round-robins XCDs on bid%8
  const int bh  = xcd * (nbh >> 3) + (idx >> 4);
  const int qt  = idx & 15;
  const int b = bh >> 3, h = bh & 7;

  const int wrow = wave * 16;                // this wave's q-row base within the 128-tile

  const f16* Qb = QK + (size_t)(b * SEQ + qt * 128 + wrow) * 1536 + h * 96;
  const f16* Kb = QK + (size_t)(b * SEQ) * 1536 + 768 + h * 96;
  const f16* Vb = Vt + (size_t)bh * HDIM * SEQ;

  f16x8 qf[3];
#pragma unroll
  for (int kc = 0; kc < 3; kc++)
    qf[kc] = *(const f16x8*)(Qb + (size_t)l16 * 1536 + kc * 32 + quad * 8);

  f32x4 oacc[6];
#pragma unroll
  for (int dj = 0; dj < 6; dj++) oacc[dj] = f32x4{0.f, 0.f, 0.f, 0.f};
  f32x4 m_run = f32x4{-1e30f, -1e30f, -1e30f, -1e30f};
  f32x4 l_run = f32x4{0.f, 0.f, 0.f, 0.f};

  for (int kt = 0; kt < SEQ / 128; kt++) {
    __syncthreads();
    {
      const f16* kt_base = Kb + (size_t)(kt * 128) * 1536;
#pragma unroll
      for (int i = 0; i < 3; i++) {
        const int c = i * 512 + tid;            // 1536 chunks of 8 f16
        const int row = c / 12, col = (c % 12) * 8;
        *(uint4*)&sK[row][col] = *(const uint4*)(kt_base + (size_t)row * 1536 + col);
      }
    }
    __syncthreads();

    // ---- QK^T ----
    f32x4 sacc[8];
#pragma unroll
    for (int j = 0; j < 8; j++) sacc[j] = f32x4{0.f, 0.f, 0.f, 0.f};
#pragma unroll
    for (int kc = 0; kc < 3; kc++) {
#pragma unroll
      for (int j = 0; j < 8; j++) {
        f16x8 kf = *(const f16x8*)&sK[j * 16 + l16][kc * 32 + quad * 8];
        sacc[j] = __builtin_amdgcn_mfma_f32_16x16x32_f16(qf[kc], kf, sacc[j], 0, 0, 0);
      }
    }

    // ---- stats: max, alpha, rescale ----
    f32x4 vmx = sacc[0];
#pragma unroll
    for (int j = 1; j < 8; j++) vmx = vmax4(vmx, sacc[j]);
    for (int m = 1; m < 16; m <<= 1) vmx = vmax4(vmx, shflx4(vmx, m));
    const f32x4 nm = vmax4(m_run, vmx);
    f32x4 alpha;
    alpha[0] = __expf(m_run[0] - nm[0]); alpha[1] = __expf(m_run[1] - nm[1]);
    alpha[2] = __expf(m_run[2] - nm[2]); alpha[3] = __expf(m_run[3] - nm[3]);
    m_run = nm;
    l_run *= alpha;
    f32x4 rsv = f32x4{0.f, 0.f, 0.f, 0.f};
#pragma unroll
    for (int dj = 0; dj < 6; dj++) oacc[dj] *= alpha;

    // ---- P writes: full 128-k width, one phase (round-0 flow) ----
    {
      const int prow = wrow + quad * 4;
#pragma unroll
      for (int j = 0; j < 8; j++) {
        f32x4 p;
        p[0] = __expf(sacc[j][0] - m_run[0]);
        p[1] = __expf(sacc[j][1] - m_run[1]);
        p[2] = __expf(sacc[j][2] - m_run[2]);
        p[3] = __expf(sacc[j][3] - m_run[3]);
        rsv += p;
        sP[prow + 0][j * 16 + l16] = (f16)p[0];
        sP[prow + 1][j * 16 + l16] = (f16)p[1];
        sP[prow + 2][j * 16 + l16] = (f16)p[2];
        sP[prow + 3][j * 16 + l16] = (f16)p[3];
      }
    }

    // ---- PV: one phase over the full 128-k width ----
#pragma unroll
    for (int kc2 = 0; kc2 < 4; kc2++) {
      f16x8 pf = *(const f16x8*)&sP[wrow + l16][kc2 * 32 + quad * 8];
#pragma unroll
      for (int dj = 0; dj < 6; dj++) {
        f16x8 vf = *(const f16x8*)(Vb + (size_t)(dj * 16 + l16) * SEQ
                                   + kt * 128 + kc2 * 32 + quad * 8);
        oacc[dj] = __builtin_amdgcn_mfma_f32_16x16x32_f16(pf, vf, oacc[dj], 0, 0, 0);
      }
    }

    // ---- finish row sums ----
    for (int m = 1; m < 16; m <<= 1) rsv += shflx4(rsv, m);
    l_run += rsv;
  }

  const float inv_scale = 0.10206207261596577f;  // 1/sqrt(96), applied AFTER softmax per ref
#pragma unroll
  for (int r = 0; r < 4; r++) {
    const int qrow = qt * 128 + wrow + quad * 4 + r;
    const float invl = inv_scale / l_run[r];
    const size_t base = ((size_t)bh * SEQ + qrow) * HDIM;   // head-major out
#pragma unroll
    for (int dj = 0; dj < 6; dj++)
      Out[base + dj * 16 + l16] = (f16)(oacc[dj][r] * invl);
  }
}

// ---------------- launch ----------------
extern "C" void kernel_launch(void* const* d_in, const int* in_sizes, int n_in,
                              void* d_out, int out_size, void* d_ws, size_t ws_size,
                              hipStream_t stream) {
  const float* x      = (const float*)d_in[0];
  const float* w_qkv  = (const float*)d_in[1];
  const float* b_qkv  = (const float*)d_in[2];
  const float* w_proj = (const float*)d_in[3];
  const float* b_proj = (const float*)d_in[4];
  float* outF = (float*)d_out;   // fp32 output

  const size_t fixed = 256 + (size_t)QKV_COLS * EMB * 2 + (size_t)EMB * EMB * 2
                     + QKV_COLS * 4 + EMB * 4 + 256;
  const size_t perb = (size_t)4 * PB * 2;  // QK(2) + Vt(1) + attn(1) per batch, in PB units
  int nb = (ws_size >= fixed + 4 * perb) ? 4 : (ws_size >= fixed + 2 * perb) ? 2 : 1;

  char* ws = (char*)d_ws;
  ws += 256;
  f16*   wqkvT  = (f16*)ws;   ws += (size_t)QKV_COLS * EMB * 2;
  f16*   wprojT = (f16*)ws;   ws += (size_t)EMB * EMB * 2;
  float* bq     = (float*)ws; ws += (size_t)QKV_COLS * 4;
  float* bp     = (float*)ws; ws += (size_t)EMB * 4 + 256;
  f16* QK   = (f16*)ws;       ws += (size_t)nb * 2 * PB * 2;   // [nb*2048][1536]
  f16* Vt   = (f16*)ws;       ws += (size_t)nb * PB * 2;       // [nb*8][96][2048]
  f16* attn = (f16*)ws;       ws += (size_t)nb * PB * 2;       // [nb*8][2048][96] head-major

  wqkv_perm_k<<<(QKV_COLS * (EMB / 8) + 255) / 256, 256, 0, stream>>>(w_qkv, wqkvT);
  wproj_t_k<<<(EMB * (EMB / 8) + 255) / 256, 256, 0, stream>>>(w_proj, wprojT);
  bias_perm_k<<<(QKV_COLS + 255) / 256, 256, 0, stream>>>(b_qkv, bq, b_proj, bp);

  for (int outer = 0; outer < BATCH / nb; outer++) {
    const int bbase = outer * nb;
    const size_t goff = (size_t)bbase * PB;
    f16* xg = (f16*)(outF + goff);           // stage f16 x inside fp32 out region (dead before proj)
    const int n8 = (int)((size_t)nb * PB / 8);
    conv_x8_k<<<(n8 + 255) / 256, 256, 0, stream>>>(x, goff, xg, n8);

    dim3 g1(QKV_COLS / 128, nb * SEQ / 128);
    gemm_bt<1><<<g1, 256, 0, stream>>>(xg, wqkvT, bq, nullptr, QK, Vt,
                                       nb * SEQ, QKV_COLS, EMB);

    attn_k<<<dim3(16 * nb * NHEADS), 512, 0, stream>>>(QK, Vt, attn, nb * NHEADS);

    dim3 g3(EMB / 128, nb * SEQ / 128);
    gemm_bt<2><<<g3, 256, 0, stream>>>(attn, wprojT, bp, outF + goff,
                                       nullptr, nullptr,
                                       nb * SEQ, EMB, EMB);
  }
}

// Round 8
// 362.196 us; speedup vs baseline: 1.1751x; 1.1551x over previous
//
#include <hip/hip_runtime.h>
#include <hip/hip_bf16.h>

#define EMB 768
#define NHEADS 8
#define HDIM 96
#define SEQ 2048
#define BATCH 4
#define QKV_COLS 2304
#define PB ((size_t)SEQ * EMB)   // per-batch elements

typedef _Float16 f16;
typedef _Float16 f16x8 __attribute__((ext_vector_type(8)));
typedef float f32x4 __attribute__((ext_vector_type(4)));

__device__ __forceinline__ void gl_lds16(const f16* g, f16* l) {
  __builtin_amdgcn_global_load_lds((const __attribute__((address_space(1))) void*)g,
                                   (__attribute__((address_space(3))) void*)l, 16, 0, 0);
}
__device__ __forceinline__ f32x4 shflx4(f32x4 v, int m) {
  f32x4 r;
  r[0] = __shfl_xor(v[0], m); r[1] = __shfl_xor(v[1], m);
  r[2] = __shfl_xor(v[2], m); r[3] = __shfl_xor(v[3], m);
  return r;
}
__device__ __forceinline__ f32x4 vmax4(f32x4 a, f32x4 b) {
  f32x4 r;
  r[0] = fmaxf(a[0], b[0]); r[1] = fmaxf(a[1], b[1]);
  r[2] = fmaxf(a[2], b[2]); r[3] = fmaxf(a[3], b[3]);
  return r;
}

// ---------------- conversions ----------------
__global__ __launch_bounds__(256) void conv_x8_k(const float* __restrict__ in, size_t in_off,
                                                 f16* __restrict__ out, int n8) {
  int i = blockIdx.x * 256 + threadIdx.x;
  if (i >= n8) return;
  const float4 a = *(const float4*)(in + in_off + (size_t)i * 8);
  const float4 b = *(const float4*)(in + in_off + (size_t)i * 8 + 4);
  f16x8 o;
  o[0] = (f16)a.x; o[1] = (f16)a.y; o[2] = (f16)a.z; o[3] = (f16)a.w;
  o[4] = (f16)b.x; o[5] = (f16)b.y; o[6] = (f16)b.z; o[7] = (f16)b.w;
  *(f16x8*)(out + (size_t)i * 8) = o;
}

// qkv weight: transpose + column-permute. out[col'][r], col' = s*768+h*96+d,
// original col c = h*288+d*3+s. Output-indexed -> coalesced 16B writes.
__global__ __launch_bounds__(256) void wqkv_perm_k(const float* __restrict__ in,
                                                   f16* __restrict__ out) {
  int t = blockIdx.x * 256 + threadIdx.x;          // 0 .. 2304*96-1
  if (t >= QKV_COLS * (EMB / 8)) return;
  const int colp = t / (EMB / 8);
  const int r8 = (t - colp * (EMB / 8)) * 8;
  const int s = colp / 768, rem = colp - s * 768;
  const int h = rem / 96, d = rem - h * 96;
  const int c = h * 288 + d * 3 + s;
  f16x8 o;
#pragma unroll
  for (int i = 0; i < 8; i++) o[i] = (f16)in[(size_t)(r8 + i) * QKV_COLS + c];
  *(f16x8*)(out + (size_t)colp * EMB + r8) = o;
}

// proj weight: plain transpose, output-indexed.
__global__ __launch_bounds__(256) void wproj_t_k(const float* __restrict__ in,
                                                 f16* __restrict__ out) {
  int t = blockIdx.x * 256 + threadIdx.x;          // 0 .. 768*96-1
  if (t >= EMB * (EMB / 8)) return;
  const int cp = t / (EMB / 8);
  const int r8 = (t - cp * (EMB / 8)) * 8;
  f16x8 o;
#pragma unroll
  for (int i = 0; i < 8; i++) o[i] = (f16)in[(size_t)(r8 + i) * EMB + cp];
  *(f16x8*)(out + (size_t)cp * EMB + r8) = o;
}

// bias: permute qkv bias to col' space; copy proj bias.
__global__ __launch_bounds__(256) void bias_perm_k(const float* __restrict__ bq_in,
                                                   float* __restrict__ bq_out,
                                                   const float* __restrict__ bp_in,
                                                   float* __restrict__ bp_out) {
  int i = blockIdx.x * 256 + threadIdx.x;
  if (i < QKV_COLS) {
    const int s = i / 768, rem = i - s * 768;
    const int h = rem / 96, d = rem - h * 96;
    bq_out[i] = bq_in[h * 288 + d * 3 + s];
  }
  if (i < EMB) bp_out[i] = bp_in[i];
}

// ---------------- bt-GEMM: C[M,N] = A[M,K] @ Bt[N,K]^T + bias ----------------
// MODE 0: fp32 store to Cout [M,N], A row-major [M][Kd]
// MODE 1 (permuted qkv): tile_n < 1536 -> QK[row][1536] direct (coalesced);
//                        tile_n >= 1536 -> V: LDS transpose -> Vt[bh][d][n] coalesced
// MODE 2: like MODE 0 but A is head-major [b*8+h][2048][96]; k -> (h = k/96, d = k%96).
//         32-wide k-chunks never straddle heads (96 = 3*32), so h = k0/96 per chunk.
template<int MODE>
__global__ __launch_bounds__(256) void gemm_bt(
    const f16* __restrict__ A, const f16* __restrict__ Bt,
    const float* __restrict__ bias, float* __restrict__ Cout,
    f16* __restrict__ QK, f16* __restrict__ Vt,
    int M, int N, int Kd)
{
  __shared__ f16 smem[MODE == 1 ? 17408 : 8192];   // sA[4096]+sB[4096]; V-epilogue reuses as sT[128][136]
  f16* sA = smem;
  f16* sB = smem + 4096;
  const int tid  = threadIdx.x;
  const int wave = tid >> 6, lane = tid & 63;
  const int quad = lane >> 4, l16 = lane & 15;
  const int tile_m = blockIdx.y * 128, tile_n = blockIdx.x * 128;
  const int wm = (wave >> 1) * 64, wn = (wave & 1) * 64;

  f32x4 acc[4][4];
  for (int i = 0; i < 4; i++)
    for (int j = 0; j < 4; j++)
      acc[i][j] = f32x4{0.f, 0.f, 0.f, 0.f};

  for (int k0 = 0; k0 < Kd; k0 += 32) {
    __syncthreads();
#pragma unroll
    for (int it = 0; it < 2; it++) {
      const int ch  = (it * 4 + wave) * 64 + lane;   // 0..511
      const int row = ch >> 2, c8 = (ch & 3) * 8;
      if (MODE == 2) {
        const int grow = tile_m + row;
        const int bb = grow >> 11, n = grow & 2047;
        const int hh = k0 / 96, d0 = k0 - hh * 96 + c8;
        gl_lds16(A + ((size_t)(bb * NHEADS + hh) * SEQ + n) * HDIM + d0,
                 &sA[(it * 4 + wave) * 512]);
      } else {
        gl_lds16(A + (size_t)(tile_m + row) * Kd + k0 + c8, &sA[(it * 4 + wave) * 512]);
      }
      gl_lds16(Bt + (size_t)(tile_n + row) * Kd + k0 + c8, &sB[(it * 4 + wave) * 512]);
    }
    __syncthreads();

    f16x8 af[4], bfr[4];
    for (int i = 0; i < 4; i++) af[i]  = *(const f16x8*)&sA[(wm + i * 16 + l16) * 32 + quad * 8];
    for (int j = 0; j < 4; j++) bfr[j] = *(const f16x8*)&sB[(wn + j * 16 + l16) * 32 + quad * 8];
    for (int i = 0; i < 4; i++)
      for (int j = 0; j < 4; j++)
        acc[i][j] = __builtin_amdgcn_mfma_f32_16x16x32_f16(af[i], bfr[j], acc[i][j], 0, 0, 0);
  }

  // epilogue: C layout col=lane&15, row=quad*4+reg
  if (MODE == 1 && tile_n >= 1536) {
    // ---- V tile: LDS transpose then coalesced Vt writes ----
    __syncthreads();   // sA/sB dead, safe to overwrite
    f16* sT = smem;    // [128][136]
    for (int j = 0; j < 4; j++) {
      const int cl = wn + j * 16 + l16;
      const float bv = bias[tile_n + cl];
      for (int i = 0; i < 4; i++)
        for (int r = 0; r < 4; r++)
          sT[cl * 136 + wm + i * 16 + quad * 4 + r] = (f16)(acc[i][j][r] + bv);
    }
    __syncthreads();
    const int bb = tile_m >> 11;          // group-local batch
    const int n0 = tile_m & 2047;
#pragma unroll
    for (int l = 0; l < 8; l++) {
      const int cc = l * 256 + tid;       // 0..2047 chunks of 8 f16
      const int rh = cc >> 4, nof = (cc & 15) * 8;
      const int hd = (tile_n - 1536) + rh;
      const int h = hd / 96, d = hd - h * 96;
      f16x8 v = *(const f16x8*)&sT[rh * 136 + nof];
      *(f16x8*)(Vt + ((size_t)(bb * NHEADS + h) * HDIM + d) * SEQ + n0 + nof) = v;
    }
  } else {
    for (int j = 0; j < 4; j++) {
      const int col = tile_n + wn + j * 16 + l16;
      const float bv = bias[col];
      for (int i = 0; i < 4; i++) {
        for (int r = 0; r < 4; r++) {
          const int row = tile_m + wm + i * 16 + quad * 4 + r;
          const float fv = acc[i][j][r] + bv;
          if (MODE != 1) Cout[(size_t)row * N + col] = fv;
          else           QK  [(size_t)row * 1536 + col] = (f16)fv;  // Q cols 0..767, K 768..1535
        }
      }
    }
  }
}

// ---------------- flash attention ----------------
// r8: V staged in LDS (was global per-wave in PV: 8x redundant L2 traffic + the
// dominant exposed latency). To fit 64 KB, all three tiles are swizzled (address
// bijections, identical formula on write & read; all <=2-way bank conflicts):
//   sK[128][96]: 16B-unit rotation  phys = (u + row) % 12     (12 units/row)
//   sV[96][128]: 16B-unit XOR       phys = u ^ (d & 15)       (16 units/row)
//   sP[128][64]: 16B-unit XOR       phys = u ^ (row & 7)      (8 units/row, two-phase)
// Total 24576 + 24576 + 16384 = 65536 B. Flow = r4's two-phase P->PV.
// Geometry unchanged: 512 thr = 8 waves x 16 q-rows, head-major Out, XCD swizzle,
// 2 blocks/CU (128 KB < 160 KB LDS pool).
__global__ __launch_bounds__(512, 4) void attn_k(
    const f16* __restrict__ QK, const f16* __restrict__ Vt,
    f16* __restrict__ Out /* [nb*8][2048][96] f16 */, int nbh)
{
  __shared__ f16 sK[128 * 96];
  __shared__ f16 sV[96 * 128];
  __shared__ f16 sP[128 * 64];
  const int tid  = threadIdx.x;
  const int wave = tid >> 6, lane = tid & 63;
  const int quad = lane >> 4, l16 = lane & 15;

  const int bid = blockIdx.x;
  const int xcd = bid & 7, idx = bid >> 3;   // dispatch round-robins XCDs on bid%8
  const int bh  = xcd * (nbh >> 3) + (idx >> 4);
  const int qt  = idx & 15;
  const int b = bh >> 3, h = bh & 7;

  const int wrow = wave * 16;                // this wave's q-row base within the 128-tile

  const f16* Qb = QK + (size_t)(b * SEQ + qt * 128 + wrow) * 1536 + h * 96;
  const f16* Kb = QK + (size_t)(b * SEQ) * 1536 + 768 + h * 96;
  const f16* Vb = Vt + (size_t)bh * HDIM * SEQ;

  f16x8 qf[3];
#pragma unroll
  for (int kc = 0; kc < 3; kc++)
    qf[kc] = *(const f16x8*)(Qb + (size_t)l16 * 1536 + kc * 32 + quad * 8);

  f32x4 oacc[6];
#pragma unroll
  for (int dj = 0; dj < 6; dj++) oacc[dj] = f32x4{0.f, 0.f, 0.f, 0.f};
  f32x4 m_run = f32x4{-1e30f, -1e30f, -1e30f, -1e30f};
  f32x4 l_run = f32x4{0.f, 0.f, 0.f, 0.f};

  for (int kt = 0; kt < SEQ / 128; kt++) {
    __syncthreads();
    {
      const f16* kt_base = Kb + (size_t)(kt * 128) * 1536;
      const f16* vt_base = Vb + kt * 128;
#pragma unroll
      for (int i = 0; i < 3; i++) {
        // K: 1536 chunks = 128 rows x 12 units; rotation-swizzled dest
        const int ck = i * 512 + tid;
        const int krow = ck / 12, ku = ck - krow * 12;
        *(uint4*)&sK[krow * 96 + ((ku + krow) % 12) * 8] =
            *(const uint4*)(kt_base + (size_t)krow * 1536 + ku * 8);
        // V: 1536 chunks = 96 rows x 16 units; XOR-swizzled dest
        const int cv = i * 512 + tid;
        const int vd = cv >> 4, vu = cv & 15;
        *(uint4*)&sV[vd * 128 + (vu ^ (vd & 15)) * 8] =
            *(const uint4*)(vt_base + (size_t)vd * SEQ + vu * 8);
      }
    }
    __syncthreads();

    // ---- QK^T (kf from rotation-swizzled sK) ----
    f32x4 sacc[8];
#pragma unroll
    for (int j = 0; j < 8; j++) sacc[j] = f32x4{0.f, 0.f, 0.f, 0.f};
#pragma unroll
    for (int kc = 0; kc < 3; kc++) {
#pragma unroll
      for (int j = 0; j < 8; j++) {
        const int krow = j * 16 + l16;
        const f16x8 kf = *(const f16x8*)&sK[krow * 96 + ((kc * 4 + quad + krow) % 12) * 8];
        sacc[j] = __builtin_amdgcn_mfma_f32_16x16x32_f16(qf[kc], kf, sacc[j], 0, 0, 0);
      }
    }

    // ---- stats: max, alpha, rescale ----
    f32x4 vmx = sacc[0];
#pragma unroll
    for (int j = 1; j < 8; j++) vmx = vmax4(vmx, sacc[j]);
    for (int m = 1; m < 16; m <<= 1) vmx = vmax4(vmx, shflx4(vmx, m));
    const f32x4 nm = vmax4(m_run, vmx);
    f32x4 alpha;
    alpha[0] = __expf(m_run[0] - nm[0]); alpha[1] = __expf(m_run[1] - nm[1]);
    alpha[2] = __expf(m_run[2] - nm[2]); alpha[3] = __expf(m_run[3] - nm[3]);
    m_run = nm;
    l_run *= alpha;
    f32x4 rsv = f32x4{0.f, 0.f, 0.f, 0.f};
#pragma unroll
    for (int dj = 0; dj < 6; dj++) oacc[dj] *= alpha;

    // ---- two 64-k halves: write P half (XOR-swizzled sP) -> PV half (vf from LDS) ----
#pragma unroll
    for (int c2 = 0; c2 < 2; c2++) {
      const int prow = wrow + quad * 4;
#pragma unroll
      for (int jl = 0; jl < 4; jl++) {
        const int j = c2 * 4 + jl;
        f32x4 p;
        p[0] = __expf(sacc[j][0] - m_run[0]);
        p[1] = __expf(sacc[j][1] - m_run[1]);
        p[2] = __expf(sacc[j][2] - m_run[2]);
        p[3] = __expf(sacc[j][3] - m_run[3]);
        rsv += p;
        const int unit = jl * 2 + (l16 >> 3);   // 16B unit of col = jl*16+l16
        const int within = l16 & 7;
#pragma unroll
        for (int rr = 0; rr < 4; rr++) {
          const int row = prow + rr;
          sP[row * 64 + (unit ^ (row & 7)) * 8 + within] = (f16)p[rr];
        }
      }
#pragma unroll
      for (int kc2 = 0; kc2 < 2; kc2++) {
        const f16x8 pf = *(const f16x8*)&sP[(wrow + l16) * 64
                                           + ((kc2 * 4 + quad) ^ (l16 & 7)) * 8];
#pragma unroll
        for (int dj = 0; dj < 6; dj++) {
          const int vph = (c2 * 8 + kc2 * 4 + quad) ^ l16;   // d&15 == l16
          const f16x8 vf = *(const f16x8*)&sV[(dj * 16 + l16) * 128 + vph * 8];
          oacc[dj] = __builtin_amdgcn_mfma_f32_16x16x32_f16(pf, vf, oacc[dj], 0, 0, 0);
        }
      }
    }

    // ---- finish row sums ----
    for (int m = 1; m < 16; m <<= 1) rsv += shflx4(rsv, m);
    l_run += rsv;
  }

  const float inv_scale = 0.10206207261596577f;  // 1/sqrt(96), applied AFTER softmax per ref
#pragma unroll
  for (int r = 0; r < 4; r++) {
    const int qrow = qt * 128 + wrow + quad * 4 + r;
    const float invl = inv_scale / l_run[r];
    const size_t base = ((size_t)bh * SEQ + qrow) * HDIM;   // head-major out
#pragma unroll
    for (int dj = 0; dj < 6; dj++)
      Out[base + dj * 16 + l16] = (f16)(oacc[dj][r] * invl);
  }
}

// ---------------- launch ----------------
extern "C" void kernel_launch(void* const* d_in, const int* in_sizes, int n_in,
                              void* d_out, int out_size, void* d_ws, size_t ws_size,
                              hipStream_t stream) {
  const float* x      = (const float*)d_in[0];
  const float* w_qkv  = (const float*)d_in[1];
  const float* b_qkv  = (const float*)d_in[2];
  const float* w_proj = (const float*)d_in[3];
  const float* b_proj = (const float*)d_in[4];
  float* outF = (float*)d_out;   // fp32 output

  const size_t fixed = 256 + (size_t)QKV_COLS * EMB * 2 + (size_t)EMB * EMB * 2
                     + QKV_COLS * 4 + EMB * 4 + 256;
  const size_t perb = (size_t)4 * PB * 2;  // QK(2) + Vt(1) + attn(1) per batch, in PB units
  int nb = (ws_size >= fixed + 4 * perb) ? 4 : (ws_size >= fixed + 2 * perb) ? 2 : 1;

  char* ws = (char*)d_ws;
  ws += 256;
  f16*   wqkvT  = (f16*)ws;   ws += (size_t)QKV_COLS * EMB * 2;
  f16*   wprojT = (f16*)ws;   ws += (size_t)EMB * EMB * 2;
  float* bq     = (float*)ws; ws += (size_t)QKV_COLS * 4;
  float* bp     = (float*)ws; ws += (size_t)EMB * 4 + 256;
  f16* QK   = (f16*)ws;       ws += (size_t)nb * 2 * PB * 2;   // [nb*2048][1536]
  f16* Vt   = (f16*)ws;       ws += (size_t)nb * PB * 2;       // [nb*8][96][2048]
  f16* attn = (f16*)ws;       ws += (size_t)nb * PB * 2;       // [nb*8][2048][96] head-major

  wqkv_perm_k<<<(QKV_COLS * (EMB / 8) + 255) / 256, 256, 0, stream>>>(w_qkv, wqkvT);
  wproj_t_k<<<(EMB * (EMB / 8) + 255) / 256, 256, 0, stream>>>(w_proj, wprojT);
  bias_perm_k<<<(QKV_COLS + 255) / 256, 256, 0, stream>>>(b_qkv, bq, b_proj, bp);

  for (int outer = 0; outer < BATCH / nb; outer++) {
    const int bbase = outer * nb;
    const size_t goff = (size_t)bbase * PB;
    f16* xg = (f16*)(outF + goff);           // stage f16 x inside fp32 out region (dead before proj)
    const int n8 = (int)((size_t)nb * PB / 8);
    conv_x8_k<<<(n8 + 255) / 256, 256, 0, stream>>>(x, goff, xg, n8);

    dim3 g1(QKV_COLS / 128, nb * SEQ / 128);
    gemm_bt<1><<<g1, 256, 0, stream>>>(xg, wqkvT, bq, nullptr, QK, Vt,
                                       nb * SEQ, QKV_COLS, EMB);

    attn_k<<<dim3(16 * nb * NHEADS), 512, 0, stream>>>(QK, Vt, attn, nb * NHEADS);

    dim3 g3(EMB / 128, nb * SEQ / 128);
    gemm_bt<2><<<g3, 256, 0, stream>>>(attn, wprojT, bp, outF + goff,
                                       nullptr, nullptr,
                                       nb * SEQ, EMB, EMB);
  }
}

// Round 10
// 345.533 us; speedup vs baseline: 1.2318x; 1.0482x over previous
//
#include <hip/hip_runtime.h>
#include <hip/hip_bf16.h>

#define EMB 768
#define NHEADS 8
#define HDIM 96
#define SEQ 2048
#define BATCH 4
#define QKV_COLS 2304
#define PB ((size_t)SEQ * EMB)   // per-batch elements

typedef _Float16 f16;
typedef _Float16 f16x8 __attribute__((ext_vector_type(8)));
typedef float f32x4 __attribute__((ext_vector_type(4)));

__device__ __forceinline__ void gl_lds16(const f16* g, f16* l) {
  __builtin_amdgcn_global_load_lds((const __attribute__((address_space(1))) void*)g,
                                   (__attribute__((address_space(3))) void*)l, 16, 0, 0);
}
__device__ __forceinline__ f32x4 shflx4(f32x4 v, int m) {
  f32x4 r;
  r[0] = __shfl_xor(v[0], m); r[1] = __shfl_xor(v[1], m);
  r[2] = __shfl_xor(v[2], m); r[3] = __shfl_xor(v[3], m);
  return r;
}
__device__ __forceinline__ f32x4 vmax4(f32x4 a, f32x4 b) {
  f32x4 r;
  r[0] = fmaxf(a[0], b[0]); r[1] = fmaxf(a[1], b[1]);
  r[2] = fmaxf(a[2], b[2]); r[3] = fmaxf(a[3], b[3]);
  return r;
}

// ---------------- conversions ----------------
__global__ __launch_bounds__(256) void conv_x8_k(const float* __restrict__ in, size_t in_off,
                                                 f16* __restrict__ out, int n8) {
  int i = blockIdx.x * 256 + threadIdx.x;
  if (i >= n8) return;
  const float4 a = *(const float4*)(in + in_off + (size_t)i * 8);
  const float4 b = *(const float4*)(in + in_off + (size_t)i * 8 + 4);
  f16x8 o;
  o[0] = (f16)a.x; o[1] = (f16)a.y; o[2] = (f16)a.z; o[3] = (f16)a.w;
  o[4] = (f16)b.x; o[5] = (f16)b.y; o[6] = (f16)b.z; o[7] = (f16)b.w;
  *(f16x8*)(out + (size_t)i * 8) = o;
}

// qkv weight: transpose + column-permute. out[col'][r], col' = s*768+h*96+d,
// original col c = h*288+d*3+s. Output-indexed -> coalesced 16B writes.
__global__ __launch_bounds__(256) void wqkv_perm_k(const float* __restrict__ in,
                                                   f16* __restrict__ out) {
  int t = blockIdx.x * 256 + threadIdx.x;          // 0 .. 2304*96-1
  if (t >= QKV_COLS * (EMB / 8)) return;
  const int colp = t / (EMB / 8);
  const int r8 = (t - colp * (EMB / 8)) * 8;
  const int s = colp / 768, rem = colp - s * 768;
  const int h = rem / 96, d = rem - h * 96;
  const int c = h * 288 + d * 3 + s;
  f16x8 o;
#pragma unroll
  for (int i = 0; i < 8; i++) o[i] = (f16)in[(size_t)(r8 + i) * QKV_COLS + c];
  *(f16x8*)(out + (size_t)colp * EMB + r8) = o;
}

// proj weight: plain transpose, output-indexed.
__global__ __launch_bounds__(256) void wproj_t_k(const float* __restrict__ in,
                                                 f16* __restrict__ out) {
  int t = blockIdx.x * 256 + threadIdx.x;          // 0 .. 768*96-1
  if (t >= EMB * (EMB / 8)) return;
  const int cp = t / (EMB / 8);
  const int r8 = (t - cp * (EMB / 8)) * 8;
  f16x8 o;
#pragma unroll
  for (int i = 0; i < 8; i++) o[i] = (f16)in[(size_t)(r8 + i) * EMB + cp];
  *(f16x8*)(out + (size_t)cp * EMB + r8) = o;
}

// bias: permute qkv bias to col' space; copy proj bias.
__global__ __launch_bounds__(256) void bias_perm_k(const float* __restrict__ bq_in,
                                                   float* __restrict__ bq_out,
                                                   const float* __restrict__ bp_in,
                                                   float* __restrict__ bp_out) {
  int i = blockIdx.x * 256 + threadIdx.x;
  if (i < QKV_COLS) {
    const int s = i / 768, rem = i - s * 768;
    const int h = rem / 96, d = rem - h * 96;
    bq_out[i] = bq_in[h * 288 + d * 3 + s];
  }
  if (i < EMB) bp_out[i] = bp_in[i];
}

// ---------------- bt-GEMM: C[M,N] = A[M,K] @ Bt[N,K]^T + bias ----------------
// MODE 0: fp32 store to Cout [M,N], A row-major [M][Kd]
// MODE 1 (permuted qkv): tile_n < 1536 -> QK[row][1536] direct (coalesced);
//                        tile_n >= 1536 -> V: LDS transpose -> Vt[bh][d][n] coalesced
// MODE 2: like MODE 0 but A is head-major [b*8+h][2048][96]; k -> (h = k/96, d = k%96).
//         32-wide k-chunks never straddle heads (96 = 3*32), so h = k0/96 per chunk.
template<int MODE>
__global__ __launch_bounds__(256) void gemm_bt(
    const f16* __restrict__ A, const f16* __restrict__ Bt,
    const float* __restrict__ bias, float* __restrict__ Cout,
    f16* __restrict__ QK, f16* __restrict__ Vt,
    int M, int N, int Kd)
{
  __shared__ f16 smem[MODE == 1 ? 17408 : 8192];   // sA[4096]+sB[4096]; V-epilogue reuses as sT[128][136]
  f16* sA = smem;
  f16* sB = smem + 4096;
  const int tid  = threadIdx.x;
  const int wave = tid >> 6, lane = tid & 63;
  const int quad = lane >> 4, l16 = lane & 15;
  const int tile_m = blockIdx.y * 128, tile_n = blockIdx.x * 128;
  const int wm = (wave >> 1) * 64, wn = (wave & 1) * 64;

  f32x4 acc[4][4];
  for (int i = 0; i < 4; i++)
    for (int j = 0; j < 4; j++)
      acc[i][j] = f32x4{0.f, 0.f, 0.f, 0.f};

  for (int k0 = 0; k0 < Kd; k0 += 32) {
    __syncthreads();
#pragma unroll
    for (int it = 0; it < 2; it++) {
      const int ch  = (it * 4 + wave) * 64 + lane;   // 0..511
      const int row = ch >> 2, c8 = (ch & 3) * 8;
      if (MODE == 2) {
        const int grow = tile_m + row;
        const int bb = grow >> 11, n = grow & 2047;
        const int hh = k0 / 96, d0 = k0 - hh * 96 + c8;
        gl_lds16(A + ((size_t)(bb * NHEADS + hh) * SEQ + n) * HDIM + d0,
                 &sA[(it * 4 + wave) * 512]);
      } else {
        gl_lds16(A + (size_t)(tile_m + row) * Kd + k0 + c8, &sA[(it * 4 + wave) * 512]);
      }
      gl_lds16(Bt + (size_t)(tile_n + row) * Kd + k0 + c8, &sB[(it * 4 + wave) * 512]);
    }
    __syncthreads();

    f16x8 af[4], bfr[4];
    for (int i = 0; i < 4; i++) af[i]  = *(const f16x8*)&sA[(wm + i * 16 + l16) * 32 + quad * 8];
    for (int j = 0; j < 4; j++) bfr[j] = *(const f16x8*)&sB[(wn + j * 16 + l16) * 32 + quad * 8];
    for (int i = 0; i < 4; i++)
      for (int j = 0; j < 4; j++)
        acc[i][j] = __builtin_amdgcn_mfma_f32_16x16x32_f16(af[i], bfr[j], acc[i][j], 0, 0, 0);
  }

  // epilogue: C layout col=lane&15, row=quad*4+reg
  if (MODE == 1 && tile_n >= 1536) {
    // ---- V tile: LDS transpose then coalesced Vt writes ----
    __syncthreads();   // sA/sB dead, safe to overwrite
    f16* sT = smem;    // [128][136]
    for (int j = 0; j < 4; j++) {
      const int cl = wn + j * 16 + l16;
      const float bv = bias[tile_n + cl];
      for (int i = 0; i < 4; i++)
        for (int r = 0; r < 4; r++)
          sT[cl * 136 + wm + i * 16 + quad * 4 + r] = (f16)(acc[i][j][r] + bv);
    }
    __syncthreads();
    const int bb = tile_m >> 11;          // group-local batch
    const int n0 = tile_m & 2047;
#pragma unroll
    for (int l = 0; l < 8; l++) {
      const int cc = l * 256 + tid;       // 0..2047 chunks of 8 f16
      const int rh = cc >> 4, nof = (cc & 15) * 8;
      const int hd = (tile_n - 1536) + rh;
      const int h = hd / 96, d = hd - h * 96;
      f16x8 v = *(const f16x8*)&sT[rh * 136 + nof];
      *(f16x8*)(Vt + ((size_t)(bb * NHEADS + h) * HDIM + d) * SEQ + n0 + nof) = v;
    }
  } else {
    for (int j = 0; j < 4; j++) {
      const int col = tile_n + wn + j * 16 + l16;
      const float bv = bias[col];
      for (int i = 0; i < 4; i++) {
        for (int r = 0; r < 4; r++) {
          const int row = tile_m + wm + i * 16 + quad * 4 + r;
          const float fv = acc[i][j][r] + bv;
          if (MODE != 1) Cout[(size_t)row * N + col] = fv;
          else           QK  [(size_t)row * 1536 + col] = (f16)fv;  // Q cols 0..767, K 768..1535
        }
      }
    }
  }
}

// ---------------- flash attention ----------------
// r9 (resubmission -- r9 bench died with SIGABRT in the container; full OOB audit
// of every r8->r9 delta found no out-of-bounds access, sP is wave-private, and all
// pre-attn kernels are byte-identical to the r8 pass, so treating as infra flake
// per the r6 precedent).
// LDS-pipe was saturated in r8 (kf+vf b128 reads ~70% of the bill, each wave
// rereading the whole K/V tile for only 16 q-rows of work). Back to r0's proven
// 4-wave/256-thread geometry (wave owns 32 q-rows, ti=2): each kf/vf read now
// feeds TWO MFMAs -> kf/vf wave-instructions halve per unit work; bpermute count
// also halves. Keeps r8's staged+swizzled sK/sV/sP (formulas verbatim), r4's
// head-major Out, XCD swizzle. Grid 512 blocks, 2 blocks/CU (LDS-capped),
// 8 waves/CU -- occupancy traded for per-wave operand reuse, which is the right
// trade when the LDS pipe (not latency) is the limiter.
//   sK[128][96]: 16B-unit rotation  phys = (u + row) % 12
//   sV[96][128]: 16B-unit XOR       phys = u ^ (d & 15)
//   sP[128][64]: 16B-unit XOR       phys = u ^ (row & 7)   (two 64-k halves)
__global__ __launch_bounds__(256, 2) void attn_k(
    const f16* __restrict__ QK, const f16* __restrict__ Vt,
    f16* __restrict__ Out /* [nb*8][2048][96] f16 */, int nbh)
{
  __shared__ f16 sK[128 * 96];
  __shared__ f16 sV[96 * 128];
  __shared__ f16 sP[128 * 64];
  const int tid  = threadIdx.x;
  const int wave = tid >> 6, lane = tid & 63;
  const int quad = lane >> 4, l16 = lane & 15;

  const int bid = blockIdx.x;
  const int xcd = bid & 7, idx = bid >> 3;   // dispatch round-robins XCDs on bid%8
  const int bh  = xcd * (nbh >> 3) + (idx >> 4);
  const int qt  = idx & 15;
  const int b = bh >> 3, h = bh & 7;

  const int wrow = wave * 32;                // this wave's q-row base (32 rows, ti=2)

  const f16* Qb = QK + (size_t)(b * SEQ + qt * 128 + wrow) * 1536 + h * 96;
  const f16* Kb = QK + (size_t)(b * SEQ) * 1536 + 768 + h * 96;
  const f16* Vb = Vt + (size_t)bh * HDIM * SEQ;

  f16x8 qf[2][3];
#pragma unroll
  for (int ti = 0; ti < 2; ti++)
#pragma unroll
    for (int kc = 0; kc < 3; kc++)
      qf[ti][kc] = *(const f16x8*)(Qb + (size_t)(ti * 16 + l16) * 1536 + kc * 32 + quad * 8);

  f32x4 oacc[2][6];
#pragma unroll
  for (int ti = 0; ti < 2; ti++)
#pragma unroll
    for (int dj = 0; dj < 6; dj++)
      oacc[ti][dj] = f32x4{0.f, 0.f, 0.f, 0.f};
  f32x4 m_run[2], l_run[2];
#pragma unroll
  for (int ti = 0; ti < 2; ti++) {
    m_run[ti] = f32x4{-1e30f, -1e30f, -1e30f, -1e30f};
    l_run[ti] = f32x4{0.f, 0.f, 0.f, 0.f};
  }

  for (int kt = 0; kt < SEQ / 128; kt++) {
    __syncthreads();
    {
      const f16* kt_base = Kb + (size_t)(kt * 128) * 1536;
      const f16* vt_base = Vb + kt * 128;
#pragma unroll
      for (int i = 0; i < 6; i++) {
        // K: 1536 chunks = 128 rows x 12 units; rotation-swizzled dest
        const int ck = i * 256 + tid;
        const int krow = ck / 12, ku = ck - krow * 12;
        *(uint4*)&sK[krow * 96 + ((ku + krow) % 12) * 8] =
            *(const uint4*)(kt_base + (size_t)krow * 1536 + ku * 8);
        // V: 1536 chunks = 96 rows x 16 units; XOR-swizzled dest
        const int cv = i * 256 + tid;
        const int vd = cv >> 4, vu = cv & 15;
        *(uint4*)&sV[vd * 128 + (vu ^ (vd & 15)) * 8] =
            *(const uint4*)(vt_base + (size_t)vd * SEQ + vu * 8);
      }
    }
    __syncthreads();

    // ---- QK^T: each kf read feeds both ti MFMAs ----
    f32x4 sacc[2][8];
#pragma unroll
    for (int ti = 0; ti < 2; ti++)
#pragma unroll
      for (int j = 0; j < 8; j++)
        sacc[ti][j] = f32x4{0.f, 0.f, 0.f, 0.f};
#pragma unroll
    for (int kc = 0; kc < 3; kc++) {
#pragma unroll
      for (int j = 0; j < 8; j++) {
        const int krow = j * 16 + l16;
        const f16x8 kf = *(const f16x8*)&sK[krow * 96 + ((kc * 4 + quad + krow) % 12) * 8];
        sacc[0][j] = __builtin_amdgcn_mfma_f32_16x16x32_f16(qf[0][kc], kf, sacc[0][j], 0, 0, 0);
        sacc[1][j] = __builtin_amdgcn_mfma_f32_16x16x32_f16(qf[1][kc], kf, sacc[1][j], 0, 0, 0);
      }
    }

    // ---- stats per ti: max, alpha, rescale ----
    f32x4 rsv[2];
#pragma unroll
    for (int ti = 0; ti < 2; ti++) {
      f32x4 vmx = sacc[ti][0];
#pragma unroll
      for (int j = 1; j < 8; j++) vmx = vmax4(vmx, sacc[ti][j]);
      for (int m = 1; m < 16; m <<= 1) vmx = vmax4(vmx, shflx4(vmx, m));
      const f32x4 nm = vmax4(m_run[ti], vmx);
      f32x4 alpha;
      alpha[0] = __expf(m_run[ti][0] - nm[0]); alpha[1] = __expf(m_run[ti][1] - nm[1]);
      alpha[2] = __expf(m_run[ti][2] - nm[2]); alpha[3] = __expf(m_run[ti][3] - nm[3]);
      m_run[ti] = nm;
      l_run[ti] *= alpha;
      rsv[ti] = f32x4{0.f, 0.f, 0.f, 0.f};
#pragma unroll
      for (int dj = 0; dj < 6; dj++) oacc[ti][dj] *= alpha;
    }

    // ---- two 64-k halves: write P (XOR-swizzled sP) -> PV (vf read feeds both ti) ----
#pragma unroll
    for (int c2 = 0; c2 < 2; c2++) {
#pragma unroll
      for (int ti = 0; ti < 2; ti++) {
        const int prow = wrow + ti * 16 + quad * 4;
#pragma unroll
        for (int jl = 0; jl < 4; jl++) {
          const int j = c2 * 4 + jl;
          f32x4 p;
          p[0] = __expf(sacc[ti][j][0] - m_run[ti][0]);
          p[1] = __expf(sacc[ti][j][1] - m_run[ti][1]);
          p[2] = __expf(sacc[ti][j][2] - m_run[ti][2]);
          p[3] = __expf(sacc[ti][j][3] - m_run[ti][3]);
          rsv[ti] += p;
          const int unit = jl * 2 + (l16 >> 3);   // 16B unit of col = jl*16+l16
          const int within = l16 & 7;
#pragma unroll
          for (int rr = 0; rr < 4; rr++) {
            const int row = prow + rr;
            sP[row * 64 + (unit ^ (row & 7)) * 8 + within] = (f16)p[rr];
          }
        }
      }
#pragma unroll
      for (int kc2 = 0; kc2 < 2; kc2++) {
        const f16x8 pf0 = *(const f16x8*)&sP[(wrow + l16) * 64
                                            + ((kc2 * 4 + quad) ^ (l16 & 7)) * 8];
        const f16x8 pf1 = *(const f16x8*)&sP[(wrow + 16 + l16) * 64
                                            + ((kc2 * 4 + quad) ^ (l16 & 7)) * 8];
#pragma unroll
        for (int dj = 0; dj < 6; dj++) {
          const int vph = (c2 * 8 + kc2 * 4 + quad) ^ l16;   // d&15 == l16
          const f16x8 vf = *(const f16x8*)&sV[(dj * 16 + l16) * 128 + vph * 8];
          oacc[0][dj] = __builtin_amdgcn_mfma_f32_16x16x32_f16(pf0, vf, oacc[0][dj], 0, 0, 0);
          oacc[1][dj] = __builtin_amdgcn_mfma_f32_16x16x32_f16(pf1, vf, oacc[1][dj], 0, 0, 0);
        }
      }
    }

    // ---- finish row sums ----
#pragma unroll
    for (int ti = 0; ti < 2; ti++) {
      for (int m = 1; m < 16; m <<= 1) rsv[ti] += shflx4(rsv[ti], m);
      l_run[ti] += rsv[ti];
    }
  }

  const float inv_scale = 0.10206207261596577f;  // 1/sqrt(96), applied AFTER softmax per ref
#pragma unroll
  for (int ti = 0; ti < 2; ti++) {
#pragma unroll
    for (int r = 0; r < 4; r++) {
      const int qrow = qt * 128 + wrow + ti * 16 + quad * 4 + r;
      const float invl = inv_scale / l_run[ti][r];
      const size_t base = ((size_t)bh * SEQ + qrow) * HDIM;   // head-major out
#pragma unroll
      for (int dj = 0; dj < 6; dj++)
        Out[base + dj * 16 + l16] = (f16)(oacc[ti][dj][r] * invl);
    }
  }
}

// ---------------- launch ----------------
extern "C" void kernel_launch(void* const* d_in, const int* in_sizes, int n_in,
                              void* d_out, int out_size, void* d_ws, size_t ws_size,
                              hipStream_t stream) {
  const float* x      = (const float*)d_in[0];
  const float* w_qkv  = (const float*)d_in[1];
  const float* b_qkv  = (const float*)d_in[2];
  const float* w_proj = (const float*)d_in[3];
  const float* b_proj = (const float*)d_in[4];
  float* outF = (float*)d_out;   // fp32 output

  const size_t fixed = 256 + (size_t)QKV_COLS * EMB * 2 + (size_t)EMB * EMB * 2
                     + QKV_COLS * 4 + EMB * 4 + 256;
  const size_t perb = (size_t)4 * PB * 2;  // QK(2) + Vt(1) + attn(1) per batch, in PB units
  int nb = (ws_size >= fixed + 4 * perb) ? 4 : (ws_size >= fixed + 2 * perb) ? 2 : 1;

  char* ws = (char*)d_ws;
  ws += 256;
  f16*   wqkvT  = (f16*)ws;   ws += (size_t)QKV_COLS * EMB * 2;
  f16*   wprojT = (f16*)ws;   ws += (size_t)EMB * EMB * 2;
  float* bq     = (float*)ws; ws += (size_t)QKV_COLS * 4;
  float* bp     = (float*)ws; ws += (size_t)EMB * 4 + 256;
  f16* QK   = (f16*)ws;       ws += (size_t)nb * 2 * PB * 2;   // [nb*2048][1536]
  f16* Vt   = (f16*)ws;       ws += (size_t)nb * PB * 2;       // [nb*8][96][2048]
  f16* attn = (f16*)ws;       ws += (size_t)nb * PB * 2;       // [nb*8][2048][96] head-major

  wqkv_perm_k<<<(QKV_COLS * (EMB / 8) + 255) / 256, 256, 0, stream>>>(w_qkv, wqkvT);
  wproj_t_k<<<(EMB * (EMB / 8) + 255) / 256, 256, 0, stream>>>(w_proj, wprojT);
  bias_perm_k<<<(QKV_COLS + 255) / 256, 256, 0, stream>>>(b_qkv, bq, b_proj, bp);

  for (int outer = 0; outer < BATCH / nb; outer++) {
    const int bbase = outer * nb;
    const size_t goff = (size_t)bbase * PB;
    f16* xg = (f16*)(outF + goff);           // stage f16 x inside fp32 out region (dead before proj)
    const int n8 = (int)((size_t)nb * PB / 8);
    conv_x8_k<<<(n8 + 255) / 256, 256, 0, stream>>>(x, goff, xg, n8);

    dim3 g1(QKV_COLS / 128, nb * SEQ / 128);
    gemm_bt<1><<<g1, 256, 0, stream>>>(xg, wqkvT, bq, nullptr, QK, Vt,
                                       nb * SEQ, QKV_COLS, EMB);

    attn_k<<<dim3(16 * nb * NHEADS), 256, 0, stream>>>(QK, Vt, attn, nb * NHEADS);

    dim3 g3(EMB / 128, nb * SEQ / 128);
    gemm_bt<2><<<g3, 256, 0, stream>>>(attn, wprojT, bp, outF + goff,
                                       nullptr, nullptr,
                                       nb * SEQ, EMB, EMB);
  }
}

// Round 11
// 330.247 us; speedup vs baseline: 1.2888x; 1.0463x over previous
//
#include <hip/hip_runtime.h>
#include <hip/hip_bf16.h>

#define EMB 768
#define NHEADS 8
#define HDIM 96
#define SEQ 2048
#define BATCH 4
#define QKV_COLS 2304
#define PB ((size_t)SEQ * EMB)   // per-batch elements

typedef _Float16 f16;
typedef _Float16 f16x8 __attribute__((ext_vector_type(8)));
typedef float f32x4 __attribute__((ext_vector_type(4)));

__device__ __forceinline__ void gl_lds16(const f16* g, f16* l) {
  __builtin_amdgcn_global_load_lds((const __attribute__((address_space(1))) void*)g,
                                   (__attribute__((address_space(3))) void*)l, 16, 0, 0);
}
__device__ __forceinline__ f32x4 shflx4(f32x4 v, int m) {
  f32x4 r;
  r[0] = __shfl_xor(v[0], m); r[1] = __shfl_xor(v[1], m);
  r[2] = __shfl_xor(v[2], m); r[3] = __shfl_xor(v[3], m);
  return r;
}
__device__ __forceinline__ f32x4 vmax4(f32x4 a, f32x4 b) {
  f32x4 r;
  r[0] = fmaxf(a[0], b[0]); r[1] = fmaxf(a[1], b[1]);
  r[2] = fmaxf(a[2], b[2]); r[3] = fmaxf(a[3], b[3]);
  return r;
}

// ---------------- conversions ----------------
__global__ __launch_bounds__(256) void conv_x8_k(const float* __restrict__ in, size_t in_off,
                                                 f16* __restrict__ out, int n8) {
  int i = blockIdx.x * 256 + threadIdx.x;
  if (i >= n8) return;
  const float4 a = *(const float4*)(in + in_off + (size_t)i * 8);
  const float4 b = *(const float4*)(in + in_off + (size_t)i * 8 + 4);
  f16x8 o;
  o[0] = (f16)a.x; o[1] = (f16)a.y; o[2] = (f16)a.z; o[3] = (f16)a.w;
  o[4] = (f16)b.x; o[5] = (f16)b.y; o[6] = (f16)b.z; o[7] = (f16)b.w;
  *(f16x8*)(out + (size_t)i * 8) = o;
}

// qkv weight: transpose + column-permute. out[col'][r], col' = s*768+h*96+d,
// original col c = h*288+d*3+s. Output-indexed -> coalesced 16B writes.
__global__ __launch_bounds__(256) void wqkv_perm_k(const float* __restrict__ in,
                                                   f16* __restrict__ out) {
  int t = blockIdx.x * 256 + threadIdx.x;          // 0 .. 2304*96-1
  if (t >= QKV_COLS * (EMB / 8)) return;
  const int colp = t / (EMB / 8);
  const int r8 = (t - colp * (EMB / 8)) * 8;
  const int s = colp / 768, rem = colp - s * 768;
  const int h = rem / 96, d = rem - h * 96;
  const int c = h * 288 + d * 3 + s;
  f16x8 o;
#pragma unroll
  for (int i = 0; i < 8; i++) o[i] = (f16)in[(size_t)(r8 + i) * QKV_COLS + c];
  *(f16x8*)(out + (size_t)colp * EMB + r8) = o;
}

// proj weight: plain transpose, output-indexed.
__global__ __launch_bounds__(256) void wproj_t_k(const float* __restrict__ in,
                                                 f16* __restrict__ out) {
  int t = blockIdx.x * 256 + threadIdx.x;          // 0 .. 768*96-1
  if (t >= EMB * (EMB / 8)) return;
  const int cp = t / (EMB / 8);
  const int r8 = (t - cp * (EMB / 8)) * 8;
  f16x8 o;
#pragma unroll
  for (int i = 0; i < 8; i++) o[i] = (f16)in[(size_t)(r8 + i) * EMB + cp];
  *(f16x8*)(out + (size_t)cp * EMB + r8) = o;
}

// bias: permute qkv bias to col' space; copy proj bias.
__global__ __launch_bounds__(256) void bias_perm_k(const float* __restrict__ bq_in,
                                                   float* __restrict__ bq_out,
                                                   const float* __restrict__ bp_in,
                                                   float* __restrict__ bp_out) {
  int i = blockIdx.x * 256 + threadIdx.x;
  if (i < QKV_COLS) {
    const int s = i / 768, rem = i - s * 768;
    const int h = rem / 96, d = rem - h * 96;
    bq_out[i] = bq_in[h * 288 + d * 3 + s];
  }
  if (i < EMB) bp_out[i] = bp_in[i];
}

// ---------------- bt-GEMM: C[M,N] = A[M,K] @ Bt[N,K]^T + bias ----------------
// MODE 0: fp32 store to Cout [M,N], A row-major [M][Kd]
// MODE 1 (permuted qkv): tile_n < 1536 -> QK[row][1536] direct (coalesced);
//                        tile_n >= 1536 -> V: LDS transpose -> Vt[bh][d][n] coalesced
// MODE 2: like MODE 0 but A is head-major [b*8+h][2048][96]; k -> (h = k/96, d = k%96).
//         32-wide k-chunks never straddle heads (96 = 3*32), so h = k0/96 per chunk.
template<int MODE>
__global__ __launch_bounds__(256) void gemm_bt(
    const f16* __restrict__ A, const f16* __restrict__ Bt,
    const float* __restrict__ bias, float* __restrict__ Cout,
    f16* __restrict__ QK, f16* __restrict__ Vt,
    int M, int N, int Kd)
{
  __shared__ f16 smem[MODE == 1 ? 17408 : 8192];   // sA[4096]+sB[4096]; V-epilogue reuses as sT[128][136]
  f16* sA = smem;
  f16* sB = smem + 4096;
  const int tid  = threadIdx.x;
  const int wave = tid >> 6, lane = tid & 63;
  const int quad = lane >> 4, l16 = lane & 15;
  const int tile_m = blockIdx.y * 128, tile_n = blockIdx.x * 128;
  const int wm = (wave >> 1) * 64, wn = (wave & 1) * 64;

  f32x4 acc[4][4];
  for (int i = 0; i < 4; i++)
    for (int j = 0; j < 4; j++)
      acc[i][j] = f32x4{0.f, 0.f, 0.f, 0.f};

  for (int k0 = 0; k0 < Kd; k0 += 32) {
    __syncthreads();
#pragma unroll
    for (int it = 0; it < 2; it++) {
      const int ch  = (it * 4 + wave) * 64 + lane;   // 0..511
      const int row = ch >> 2, c8 = (ch & 3) * 8;
      if (MODE == 2) {
        const int grow = tile_m + row;
        const int bb = grow >> 11, n = grow & 2047;
        const int hh = k0 / 96, d0 = k0 - hh * 96 + c8;
        gl_lds16(A + ((size_t)(bb * NHEADS + hh) * SEQ + n) * HDIM + d0,
                 &sA[(it * 4 + wave) * 512]);
      } else {
        gl_lds16(A + (size_t)(tile_m + row) * Kd + k0 + c8, &sA[(it * 4 + wave) * 512]);
      }
      gl_lds16(Bt + (size_t)(tile_n + row) * Kd + k0 + c8, &sB[(it * 4 + wave) * 512]);
    }
    __syncthreads();

    f16x8 af[4], bfr[4];
    for (int i = 0; i < 4; i++) af[i]  = *(const f16x8*)&sA[(wm + i * 16 + l16) * 32 + quad * 8];
    for (int j = 0; j < 4; j++) bfr[j] = *(const f16x8*)&sB[(wn + j * 16 + l16) * 32 + quad * 8];
    for (int i = 0; i < 4; i++)
      for (int j = 0; j < 4; j++)
        acc[i][j] = __builtin_amdgcn_mfma_f32_16x16x32_f16(af[i], bfr[j], acc[i][j], 0, 0, 0);
  }

  // epilogue: C layout col=lane&15, row=quad*4+reg
  if (MODE == 1 && tile_n >= 1536) {
    // ---- V tile: LDS transpose then coalesced Vt writes ----
    __syncthreads();   // sA/sB dead, safe to overwrite
    f16* sT = smem;    // [128][136]
    for (int j = 0; j < 4; j++) {
      const int cl = wn + j * 16 + l16;
      const float bv = bias[tile_n + cl];
      for (int i = 0; i < 4; i++)
        for (int r = 0; r < 4; r++)
          sT[cl * 136 + wm + i * 16 + quad * 4 + r] = (f16)(acc[i][j][r] + bv);
    }
    __syncthreads();
    const int bb = tile_m >> 11;          // group-local batch
    const int n0 = tile_m & 2047;
#pragma unroll
    for (int l = 0; l < 8; l++) {
      const int cc = l * 256 + tid;       // 0..2047 chunks of 8 f16
      const int rh = cc >> 4, nof = (cc & 15) * 8;
      const int hd = (tile_n - 1536) + rh;
      const int h = hd / 96, d = hd - h * 96;
      f16x8 v = *(const f16x8*)&sT[rh * 136 + nof];
      *(f16x8*)(Vt + ((size_t)(bb * NHEADS + h) * HDIM + d) * SEQ + n0 + nof) = v;
    }
  } else {
    for (int j = 0; j < 4; j++) {
      const int col = tile_n + wn + j * 16 + l16;
      const float bv = bias[col];
      for (int i = 0; i < 4; i++) {
        for (int r = 0; r < 4; r++) {
          const int row = tile_m + wm + i * 16 + quad * 4 + r;
          const float fv = acc[i][j][r] + bv;
          if (MODE != 1) Cout[(size_t)row * N + col] = fv;
          else           QK  [(size_t)row * 1536 + col] = (f16)fv;  // Q cols 0..767, K 768..1535
        }
      }
    }
  }
}

// ---------------- flash attention ----------------
// r11: async staggered staging (T3/T14). K and V are consumed in different
// phases, so single-buffered prefetch works: issue global_load_lds for K(kt+1)
// right after QK^T(kt) (flies during softmax+PV), V(kt+1) right after PV(kt)
// (flies through next QK^T). Counted vmcnt(6) drains only the tile needed next;
// raw s_barrier + sched_barrier(0) fences (plain __syncthreads would emit
// vmcnt(0) and kill the overlap). gl_lds needs LINEAR LDS dest, so the r10
// swizzles move to the per-lane GLOBAL SOURCE address (inverse bijections):
//   sK dest (row,pu) <- global unit (pu - row) mod 12   [read: (u+row)%12]
//   sV dest (vd,pu)  <- global unit pu ^ (vd & 15)      [read: u ^ (vd&15)]
// Read-side formulas and ALL compute/softmax/P/PV instructions byte-identical
// to r10 (passed). Also deletes 12 ds_write b128 per wave-kt + staging regs.
__global__ __launch_bounds__(256, 2) void attn_k(
    const f16* __restrict__ QK, const f16* __restrict__ Vt,
    f16* __restrict__ Out /* [nb*8][2048][96] f16 */, int nbh)
{
  __shared__ f16 sK[128 * 96];
  __shared__ f16 sV[96 * 128];
  __shared__ f16 sP[128 * 64];
  const int tid  = threadIdx.x;
  const int wave = tid >> 6, lane = tid & 63;
  const int quad = lane >> 4, l16 = lane & 15;

  const int bid = blockIdx.x;
  const int xcd = bid & 7, idx = bid >> 3;   // dispatch round-robins XCDs on bid%8
  const int bh  = xcd * (nbh >> 3) + (idx >> 4);
  const int qt  = idx & 15;
  const int b = bh >> 3, h = bh & 7;

  const int wrow = wave * 32;                // this wave's q-row base (32 rows, ti=2)

  const f16* Qb = QK + (size_t)(b * SEQ + qt * 128 + wrow) * 1536 + h * 96;
  const f16* Kb = QK + (size_t)(b * SEQ) * 1536 + 768 + h * 96;
  const f16* Vb = Vt + (size_t)bh * HDIM * SEQ;

  // per-thread pre-swizzled staging source offsets (chunk ck = i*256 + tid):
  //  K: (krow,pu) -> src krow*1536 + ((pu - krow) mod 12)*8 ; dest linear ck*8
  //  V: (vd,pu)   -> src vd*SEQ + (pu ^ (vd&15))*8          ; dest linear ck*8
  int koff[6], voff[6];
#pragma unroll
  for (int i = 0; i < 6; i++) {
    const int ck = i * 256 + tid;
    const int krow = ck / 12, pu = ck - krow * 12;
    const int u = (pu + 12 - krow % 12) % 12;
    koff[i] = krow * 1536 + u * 8;
    const int vd = ck >> 4, pv = ck & 15;
    voff[i] = vd * SEQ + (pv ^ (vd & 15)) * 8;
  }

  f16x8 qf[2][3];
#pragma unroll
  for (int ti = 0; ti < 2; ti++)
#pragma unroll
    for (int kc = 0; kc < 3; kc++)
      qf[ti][kc] = *(const f16x8*)(Qb + (size_t)(ti * 16 + l16) * 1536 + kc * 32 + quad * 8);

  f32x4 oacc[2][6];
#pragma unroll
  for (int ti = 0; ti < 2; ti++)
#pragma unroll
    for (int dj = 0; dj < 6; dj++)
      oacc[ti][dj] = f32x4{0.f, 0.f, 0.f, 0.f};
  f32x4 m_run[2], l_run[2];
#pragma unroll
  for (int ti = 0; ti < 2; ti++) {
    m_run[ti] = f32x4{-1e30f, -1e30f, -1e30f, -1e30f};
    l_run[ti] = f32x4{0.f, 0.f, 0.f, 0.f};
  }

  // prologue: issue K(0) then V(0) (order matters for vmcnt counting)
  {
    const f16* kb = Kb;
    const f16* vb = Vb;
#pragma unroll
    for (int i = 0; i < 6; i++) gl_lds16(kb + koff[i], &sK[(i * 256 + wave * 64) * 8]);
#pragma unroll
    for (int i = 0; i < 6; i++) gl_lds16(vb + voff[i], &sV[(i * 256 + wave * 64) * 8]);
  }

  const int NT = SEQ / 128;
  for (int kt = 0; kt < NT; kt++) {
    // #1: drain K(kt) (kt=0: drain everything incl. qf to make counts exact)
    if (kt == 0) asm volatile("s_waitcnt vmcnt(0)" ::: "memory");
    else         asm volatile("s_waitcnt vmcnt(6)" ::: "memory");
    __builtin_amdgcn_s_barrier();            // #2: sK(kt) visible to all waves
    __builtin_amdgcn_sched_barrier(0);

    // ---- QK^T: each kf read feeds both ti MFMAs ----
    f32x4 sacc[2][8];
#pragma unroll
    for (int ti = 0; ti < 2; ti++)
#pragma unroll
      for (int j = 0; j < 8; j++)
        sacc[ti][j] = f32x4{0.f, 0.f, 0.f, 0.f};
#pragma unroll
    for (int kc = 0; kc < 3; kc++) {
#pragma unroll
      for (int j = 0; j < 8; j++) {
        const int krow = j * 16 + l16;
        const f16x8 kf = *(const f16x8*)&sK[krow * 96 + ((kc * 4 + quad + krow) % 12) * 8];
        sacc[0][j] = __builtin_amdgcn_mfma_f32_16x16x32_f16(qf[0][kc], kf, sacc[0][j], 0, 0, 0);
        sacc[1][j] = __builtin_amdgcn_mfma_f32_16x16x32_f16(qf[1][kc], kf, sacc[1][j], 0, 0, 0);
      }
    }

    __builtin_amdgcn_sched_barrier(0);
    __builtin_amdgcn_s_barrier();            // #3: all waves done reading sK
    if (kt < NT - 1) {                       // issue K(kt+1) -> flies during softmax+PV
      const f16* kb = Kb + (size_t)((kt + 1) * 128) * 1536;
#pragma unroll
      for (int i = 0; i < 6; i++) gl_lds16(kb + koff[i], &sK[(i * 256 + wave * 64) * 8]);
    }
    __builtin_amdgcn_sched_barrier(0);

    // ---- stats per ti: max, alpha, rescale ----
    f32x4 rsv[2];
#pragma unroll
    for (int ti = 0; ti < 2; ti++) {
      f32x4 vmx = sacc[ti][0];
#pragma unroll
      for (int j = 1; j < 8; j++) vmx = vmax4(vmx, sacc[ti][j]);
      for (int m = 1; m < 16; m <<= 1) vmx = vmax4(vmx, shflx4(vmx, m));
      const f32x4 nm = vmax4(m_run[ti], vmx);
      f32x4 alpha;
      alpha[0] = __expf(m_run[ti][0] - nm[0]); alpha[1] = __expf(m_run[ti][1] - nm[1]);
      alpha[2] = __expf(m_run[ti][2] - nm[2]); alpha[3] = __expf(m_run[ti][3] - nm[3]);
      m_run[ti] = nm;
      l_run[ti] *= alpha;
      rsv[ti] = f32x4{0.f, 0.f, 0.f, 0.f};
#pragma unroll
      for (int dj = 0; dj < 6; dj++) oacc[ti][dj] *= alpha;
    }

    // #4: drain V(kt) (last iter: nothing newer outstanding -> 0)
    if (kt < NT - 1) asm volatile("s_waitcnt vmcnt(6)" ::: "memory");
    else             asm volatile("s_waitcnt vmcnt(0)" ::: "memory");
    __builtin_amdgcn_s_barrier();            // #5: sV(kt) visible to all waves
    __builtin_amdgcn_sched_barrier(0);

    // ---- two 64-k halves: write P (XOR-swizzled sP) -> PV (vf read feeds both ti) ----
#pragma unroll
    for (int c2 = 0; c2 < 2; c2++) {
#pragma unroll
      for (int ti = 0; ti < 2; ti++) {
        const int prow = wrow + ti * 16 + quad * 4;
#pragma unroll
        for (int jl = 0; jl < 4; jl++) {
          const int j = c2 * 4 + jl;
          f32x4 p;
          p[0] = __expf(sacc[ti][j][0] - m_run[ti][0]);
          p[1] = __expf(sacc[ti][j][1] - m_run[ti][1]);
          p[2] = __expf(sacc[ti][j][2] - m_run[ti][2]);
          p[3] = __expf(sacc[ti][j][3] - m_run[ti][3]);
          rsv[ti] += p;
          const int unit = jl * 2 + (l16 >> 3);   // 16B unit of col = jl*16+l16
          const int within = l16 & 7;
#pragma unroll
          for (int rr = 0; rr < 4; rr++) {
            const int row = prow + rr;
            sP[row * 64 + (unit ^ (row & 7)) * 8 + within] = (f16)p[rr];
          }
        }
      }
#pragma unroll
      for (int kc2 = 0; kc2 < 2; kc2++) {
        const f16x8 pf0 = *(const f16x8*)&sP[(wrow + l16) * 64
                                            + ((kc2 * 4 + quad) ^ (l16 & 7)) * 8];
        const f16x8 pf1 = *(const f16x8*)&sP[(wrow + 16 + l16) * 64
                                            + ((kc2 * 4 + quad) ^ (l16 & 7)) * 8];
#pragma unroll
        for (int dj = 0; dj < 6; dj++) {
          const int vph = (c2 * 8 + kc2 * 4 + quad) ^ l16;   // d&15 == l16
          const f16x8 vf = *(const f16x8*)&sV[(dj * 16 + l16) * 128 + vph * 8];
          oacc[0][dj] = __builtin_amdgcn_mfma_f32_16x16x32_f16(pf0, vf, oacc[0][dj], 0, 0, 0);
          oacc[1][dj] = __builtin_amdgcn_mfma_f32_16x16x32_f16(pf1, vf, oacc[1][dj], 0, 0, 0);
        }
      }
    }

    __builtin_amdgcn_sched_barrier(0);
    __builtin_amdgcn_s_barrier();            // #6: all waves done reading sV
    if (kt < NT - 1) {                       // issue V(kt+1) -> flies through next QK^T
      const f16* vb = Vb + (kt + 1) * 128;
#pragma unroll
      for (int i = 0; i < 6; i++) gl_lds16(vb + voff[i], &sV[(i * 256 + wave * 64) * 8]);
    }
    __builtin_amdgcn_sched_barrier(0);

    // ---- finish row sums ----
#pragma unroll
    for (int ti = 0; ti < 2; ti++) {
      for (int m = 1; m < 16; m <<= 1) rsv[ti] += shflx4(rsv[ti], m);
      l_run[ti] += rsv[ti];
    }
  }

  const float inv_scale = 0.10206207261596577f;  // 1/sqrt(96), applied AFTER softmax per ref
#pragma unroll
  for (int ti = 0; ti < 2; ti++) {
#pragma unroll
    for (int r = 0; r < 4; r++) {
      const int qrow = qt * 128 + wrow + ti * 16 + quad * 4 + r;
      const float invl = inv_scale / l_run[ti][r];
      const size_t base = ((size_t)bh * SEQ + qrow) * HDIM;   // head-major out
#pragma unroll
      for (int dj = 0; dj < 6; dj++)
        Out[base + dj * 16 + l16] = (f16)(oacc[ti][dj][r] * invl);
    }
  }
}

// ---------------- launch ----------------
extern "C" void kernel_launch(void* const* d_in, const int* in_sizes, int n_in,
                              void* d_out, int out_size, void* d_ws, size_t ws_size,
                              hipStream_t stream) {
  const float* x      = (const float*)d_in[0];
  const float* w_qkv  = (const float*)d_in[1];
  const float* b_qkv  = (const float*)d_in[2];
  const float* w_proj = (const float*)d_in[3];
  const float* b_proj = (const float*)d_in[4];
  float* outF = (float*)d_out;   // fp32 output

  const size_t fixed = 256 + (size_t)QKV_COLS * EMB * 2 + (size_t)EMB * EMB * 2
                     + QKV_COLS * 4 + EMB * 4 + 256;
  const size_t perb = (size_t)4 * PB * 2;  // QK(2) + Vt(1) + attn(1) per batch, in PB units
  int nb = (ws_size >= fixed + 4 * perb) ? 4 : (ws_size >= fixed + 2 * perb) ? 2 : 1;

  char* ws = (char*)d_ws;
  ws += 256;
  f16*   wqkvT  = (f16*)ws;   ws += (size_t)QKV_COLS * EMB * 2;
  f16*   wprojT = (f16*)ws;   ws += (size_t)EMB * EMB * 2;
  float* bq     = (float*)ws; ws += (size_t)QKV_COLS * 4;
  float* bp     = (float*)ws; ws += (size_t)EMB * 4 + 256;
  f16* QK   = (f16*)ws;       ws += (size_t)nb * 2 * PB * 2;   // [nb*2048][1536]
  f16* Vt   = (f16*)ws;       ws += (size_t)nb * PB * 2;       // [nb*8][96][2048]
  f16* attn = (f16*)ws;       ws += (size_t)nb * PB * 2;       // [nb*8][2048][96] head-major

  wqkv_perm_k<<<(QKV_COLS * (EMB / 8) + 255) / 256, 256, 0, stream>>>(w_qkv, wqkvT);
  wproj_t_k<<<(EMB * (EMB / 8) + 255) / 256, 256, 0, stream>>>(w_proj, wprojT);
  bias_perm_k<<<(QKV_COLS + 255) / 256, 256, 0, stream>>>(b_qkv, bq, b_proj, bp);

  for (int outer = 0; outer < BATCH / nb; outer++) {
    const int bbase = outer * nb;
    const size_t goff = (size_t)bbase * PB;
    f16* xg = (f16*)(outF + goff);           // stage f16 x inside fp32 out region (dead before proj)
    const int n8 = (int)((size_t)nb * PB / 8);
    conv_x8_k<<<(n8 + 255) / 256, 256, 0, stream>>>(x, goff, xg, n8);

    dim3 g1(QKV_COLS / 128, nb * SEQ / 128);
    gemm_bt<1><<<g1, 256, 0, stream>>>(xg, wqkvT, bq, nullptr, QK, Vt,
                                       nb * SEQ, QKV_COLS, EMB);

    attn_k<<<dim3(16 * nb * NHEADS), 256, 0, stream>>>(QK, Vt, attn, nb * NHEADS);

    dim3 g3(EMB / 128, nb * SEQ / 128);
    gemm_bt<2><<<g3, 256, 0, stream>>>(attn, wprojT, bp, outF + goff,
                                       nullptr, nullptr,
                                       nb * SEQ, EMB, EMB);
  }
}